// Round 1
// 623.724 us; speedup vs baseline: 1.0595x; 1.0595x over previous
//
#include <hip/hip_runtime.h>
#include <math.h>

typedef __bf16 bf16x8 __attribute__((ext_vector_type(8)));
typedef __bf16 bf16x4 __attribute__((ext_vector_type(4)));
typedef float  f32x4  __attribute__((ext_vector_type(4)));

#define MFMA(a,b,c) __builtin_amdgcn_mfma_f32_16x16x32_bf16((a),(b),(c),0,0,0)

#define A_N   128
#define LDIM  256
#define FLATD 4096

// ---------------------------------------------------------------------------
// Convert the 6 latent weight arrays (each [4][256][256] fp32) to split bf16
// (hi + lo, lo = bf16(x - fp32(hi))). grid (128, 6) x 256; 8 elems/thread.
__global__ void k_cvt_w(const float* __restrict__ s0, const float* __restrict__ s1,
                        const float* __restrict__ s2, const float* __restrict__ s3,
                        const float* __restrict__ s4, const float* __restrict__ s5,
                        __bf16* __restrict__ dh, __bf16* __restrict__ dl) {
    const float* s;
    switch (blockIdx.y) {
        case 0: s = s0; break; case 1: s = s1; break; case 2: s = s2; break;
        case 3: s = s3; break; case 4: s = s4; break; default: s = s5; break;
    }
    size_t off  = (size_t)blockIdx.x * 2048 + threadIdx.x * 8;
    const float4* sp = (const float4*)(s + off);
    float4 x = sp[0], y = sp[1];
    float v[8] = {x.x, x.y, x.z, x.w, y.x, y.y, y.z, y.w};
    bf16x8 h, l;
    #pragma unroll
    for (int j = 0; j < 8; ++j) {
        __bf16 hh = (__bf16)v[j];
        h[j] = hh;
        l[j] = (__bf16)(v[j] - (float)hh);
    }
    size_t dst = (size_t)blockIdx.y * 262144 + off;
    *(bf16x8*)(dh + dst) = h;
    *(bf16x8*)(dl + dst) = l;
}

// ---------------------------------------------------------------------------
// Fused 4-layer latent transformer, split-bf16 (near-fp32) projections.
// One block per asset (16 rows x 256). 1024 threads = 16 waves.
// Each wave owns 16 output columns in GEMM phases (vs 32 before): same
// per-CU traffic, 2x resident waves -> 2x outstanding loads (latency-bound).
// MFMA 16x16x32 bf16 layouts (verified m89/m91):
//   A[m=lane&15][k=(lane>>4)*8+j], B[n=lane&15][k=(lane>>4)*8+j]
//   C[m=(lane>>4)*4+reg][n=lane&15]
__global__ __launch_bounds__(1024) void k_latent(
    const float* __restrict__ z,
    const __bf16* __restrict__ Wh, const __bf16* __restrict__ Wl,
    const float* __restrict__ boa,
    const float* __restrict__ g1a, const float* __restrict__ b1a,
    const float* __restrict__ fb1a, const float* __restrict__ fb2a,
    const float* __restrict__ g2a, const float* __restrict__ b2a,
    float* __restrict__ zprior, __bf16* __restrict__ Zbh, __bf16* __restrict__ Zbl)
{
    // LDS arena 57856 B. Aliases (barrier-guarded):
    //   Ph  aliases zbh (zb dead between qkv-proj and LN1)
    //   ob  aliases Qh + first 256 B of Kh (dead after scores)
    __shared__ __align__(16) char arena[57856];
    float*  zf  = (float*)arena;                    // [16][256] f32 residual
    __bf16* zbh = (__bf16*)(arena + 16384);         // [16][264]
    __bf16* zbl = (__bf16*)(arena + 24832);         // [16][264]
    __bf16* Ph  = (__bf16*)(arena + 16384);         // [8][16][32] (k-pad 0)
    __bf16* Qh  = (__bf16*)(arena + 33280);         // [8][16][32]
    __bf16* ob  = Qh;                               // [16][264]
    __bf16* Kh  = (__bf16*)(arena + 41472);         // [8][16][32]
    __bf16* Vt  = (__bf16*)(arena + 49664);         // [8][32][16] V^T compact

    const int a    = blockIdx.x;
    const int t    = threadIdx.x;
    const int w    = t >> 6;          // 0..15
    const int lane = t & 63;
    const int q    = lane >> 4;
    const int r    = lane & 15;
    const int nc   = w * 16;          // GEMM output col base for this wave
    const int head = w >> 1;          // attention head for qkv store
    const int hc   = (w & 1) * 16;    // col-half within head

    // ---- load z -> zf, zbh/zbl; emit z_prior (4 floats/thread) ----
    {
        int row = t >> 6, col = (t & 63) * 4;
        const float4 x = *(const float4*)(z + (size_t)a * 4096 + row * 256 + col);
        *(float4*)(zprior + (size_t)a * 4096 + row * 256 + col) = x;
        float v[4] = {x.x, x.y, x.z, x.w};
        float*  zr = zf  + row * 256 + col;
        __bf16* zh = zbh + row * 264 + col;
        __bf16* zl = zbl + row * 264 + col;
        #pragma unroll
        for (int j = 0; j < 4; ++j) {
            zr[j] = v[j];
            __bf16 hh = (__bf16)v[j];
            zh[j] = hh;
            zl[j] = (__bf16)(v[j] - (float)hh);
        }
    }
    __syncthreads();

    // wave w handles row w (64 lanes x 4 cols)
    auto do_ln = [&](const float* g, const float* bb) {
        int col = lane * 4;
        float* zr = zf + w * 256 + col;
        float4 v4 = *(const float4*)zr;
        float v[4] = {v4.x, v4.y, v4.z, v4.w};
        float s1 = 0.f, s2 = 0.f;
        #pragma unroll
        for (int j = 0; j < 4; ++j) { s1 += v[j]; s2 += v[j]*v[j]; }
        #pragma unroll
        for (int o = 1; o <= 32; o <<= 1) {
            s1 += __shfl_xor(s1, o);
            s2 += __shfl_xor(s2, o);
        }
        float mean = s1 * (1.0f/256.0f);
        float var  = s2 * (1.0f/256.0f) - mean * mean;
        float inv  = rsqrtf(var + 1e-5f);
        float4 g4 = *(const float4*)(g + col);
        float4 b4 = *(const float4*)(bb + col);
        float gg[4] = {g4.x, g4.y, g4.z, g4.w};
        float bbv[4] = {b4.x, b4.y, b4.z, b4.w};
        __bf16* zh = zbh + w * 264 + col;
        __bf16* zl = zbl + w * 264 + col;
        float y[4];
        #pragma unroll
        for (int j = 0; j < 4; ++j) {
            y[j] = (v[j] - mean) * inv * gg[j] + bbv[j];
            __bf16 hh = (__bf16)y[j];
            zh[j] = hh;
            zl[j] = (__bf16)(y[j] - (float)hh);
        }
        *(float4*)zr = (float4){y[0], y[1], y[2], y[3]};
    };

    const f32x4 zero4 = {0.f, 0.f, 0.f, 0.f};
    bf16x8 zer8;
    #pragma unroll
    for (int j = 0; j < 8; ++j) zer8[j] = (__bf16)0.0f;

    for (int lp = 0; lp < 4; ++lp) {
        const size_t lo0 = (size_t)lp * 65536;
        const __bf16* wqh = Wh + 0*262144 + lo0; const __bf16* wql = Wl + 0*262144 + lo0;
        const __bf16* wkh = Wh + 1*262144 + lo0; const __bf16* wkl = Wl + 1*262144 + lo0;
        const __bf16* wvh = Wh + 2*262144 + lo0; const __bf16* wvl = Wl + 2*262144 + lo0;
        const __bf16* woh = Wh + 3*262144 + lo0; const __bf16* wol = Wl + 3*262144 + lo0;
        const __bf16* f1h = Wh + 4*262144 + lo0; const __bf16* f1l = Wl + 4*262144 + lo0;
        const __bf16* f2h = Wh + 5*262144 + lo0; const __bf16* f2l = Wl + 5*262144 + lo0;
        const float* bo  = boa  + lp*256;
        const float* g1  = g1a  + lp*256; const float* b1 = b1a + lp*256;
        const float* fb1 = fb1a + lp*256; const float* fb2 = fb2a + lp*256;
        const float* g2  = g2a  + lp*256; const float* b2 = b2a + lp*256;

        const size_t wrow = (size_t)(nc + r) * 256 + q * 8;  // weight row base
        const __bf16* zA_h = zbh + r * 264 + q * 8;          // A frag base
        const __bf16* zA_l = zbl + r * 264 + q * 8;
        const __bf16* oA   = ob  + r * 264 + q * 8;

        // ---- q,k,v projections: 3 interleaved split-product chains ----
        {
            const __bf16* pq_h = wqh + wrow; const __bf16* pq_l = wql + wrow;
            const __bf16* pk_h = wkh + wrow; const __bf16* pk_l = wkl + wrow;
            const __bf16* pv_h = wvh + wrow; const __bf16* pv_l = wvl + wrow;
            f32x4 aq = zero4, ak = zero4, av = zero4;
            #pragma unroll
            for (int ks = 0; ks < 8; ++ks) {
                bf16x8 afh = *(const bf16x8*)(zA_h + ks*32);
                bf16x8 afl = *(const bf16x8*)(zA_l + ks*32);
                bf16x8 qh = *(const bf16x8*)(pq_h + ks*32);
                bf16x8 ql = *(const bf16x8*)(pq_l + ks*32);
                bf16x8 kh = *(const bf16x8*)(pk_h + ks*32);
                bf16x8 kl = *(const bf16x8*)(pk_l + ks*32);
                bf16x8 vh = *(const bf16x8*)(pv_h + ks*32);
                bf16x8 vl = *(const bf16x8*)(pv_l + ks*32);
                aq = MFMA(afh, qh, aq); aq = MFMA(afl, qh, aq); aq = MFMA(afh, ql, aq);
                ak = MFMA(afh, kh, ak); ak = MFMA(afl, kh, ak); ak = MFMA(afh, kl, ak);
                av = MFMA(afh, vh, av); av = MFMA(afl, vh, av); av = MFMA(afh, vl, av);
            }
            #pragma unroll
            for (int i = 0; i < 4; ++i) {
                int m = q*4 + i;
                Qh[(head*16 + m)*32 + hc + r] = (__bf16)aq[i];
                Kh[(head*16 + m)*32 + hc + r] = (__bf16)ak[i];
                Vt[(head*32 + hc + r)*16 + m] = (__bf16)av[i];
            }
        }
        __syncthreads();   // Qh/Kh/Vt visible; zb reads done (Ph may alias)

        // ---- scores + softmax, head w per wave (waves 0..7 only) ----
        if (w < 8) {
            bf16x8 qa = *(const bf16x8*)(Qh + (w*16 + r)*32 + q*8);
            bf16x8 ka = *(const bf16x8*)(Kh + (w*16 + r)*32 + q*8);
            f32x4 s = MFMA(qa, ka, zero4);   // S[i=q*4+reg][j=r], K = hd = 32
            #pragma unroll
            for (int i = 0; i < 4; ++i) {
                float sc = s[i] * 0.17677669529663687f;
                float mx = sc;
                #pragma unroll
                for (int o = 1; o <= 8; o <<= 1) mx = fmaxf(mx, __shfl_xor(mx, o, 16));
                float e = __expf(sc - mx);
                float sm = e;
                #pragma unroll
                for (int o = 1; o <= 8; o <<= 1) sm += __shfl_xor(sm, o, 16);
                Ph[(w*16 + q*4 + i)*32 + r]      = (__bf16)(e / sm);
                Ph[(w*16 + q*4 + i)*32 + 16 + r] = (__bf16)0.0f;   // k-pad
            }
        }
        __syncthreads();   // all Qh/Kh reads done (ob may alias)

        // ---- O = P @ V. 16 waves: head = w&7, d-half = w>>3 ----
        {
            int ph = w & 7, vnt = w >> 3;
            bf16x8 pa = *(const bf16x8*)(Ph + (ph*16 + r)*32 + q*8);
            bf16x8 vb = (q < 2)
                ? *(const bf16x8*)(Vt + (ph*32 + vnt*16 + r)*16 + q*8) : zer8;
            f32x4 o = MFMA(pa, vb, zero4);   // O[i=q*4+reg][d=vnt*16+r]
            #pragma unroll
            for (int i = 0; i < 4; ++i)
                ob[(q*4 + i)*264 + ph*32 + vnt*16 + r] = (__bf16)o[i];
        }
        __syncthreads();

        // ---- wo projection (A=ob single, split B) + bias + residual ----
        {
            const __bf16* po_h = woh + wrow; const __bf16* po_l = wol + wrow;
            f32x4 acc = zero4;
            #pragma unroll
            for (int ks = 0; ks < 8; ++ks) {
                bf16x8 af = *(const bf16x8*)(oA + ks*32);
                bf16x8 bh = *(const bf16x8*)(po_h + ks*32);
                bf16x8 bl = *(const bf16x8*)(po_l + ks*32);
                acc = MFMA(af, bh, acc);
                acc = MFMA(af, bl, acc);
            }
            #pragma unroll
            for (int i = 0; i < 4; ++i) {
                int row = q*4 + i, col = nc + r;
                zf[row*256 + col] = acc[i] + bo[col] + zf[row*256 + col];
            }
        }
        __syncthreads();
        do_ln(g1, b1);
        __syncthreads();

        // ---- FF1: relu(z @ f1^T + fb1) -> ob (split A x split B) ----
        {
            const __bf16* pf_h = f1h + wrow; const __bf16* pf_l = f1l + wrow;
            f32x4 acc = zero4;
            #pragma unroll
            for (int ks = 0; ks < 8; ++ks) {
                bf16x8 afh = *(const bf16x8*)(zA_h + ks*32);
                bf16x8 afl = *(const bf16x8*)(zA_l + ks*32);
                bf16x8 bh  = *(const bf16x8*)(pf_h + ks*32);
                bf16x8 bl  = *(const bf16x8*)(pf_l + ks*32);
                acc = MFMA(afh, bh, acc);
                acc = MFMA(afl, bh, acc);
                acc = MFMA(afh, bl, acc);
            }
            #pragma unroll
            for (int i = 0; i < 4; ++i) {
                int row = q*4 + i, col = nc + r;
                ob[row*264 + col] = (__bf16)fmaxf(acc[i] + fb1[col], 0.0f);
            }
        }
        __syncthreads();

        // ---- FF2 (A=ob single, split B) + bias + residual ----
        {
            const __bf16* pf_h = f2h + wrow; const __bf16* pf_l = f2l + wrow;
            f32x4 acc = zero4;
            #pragma unroll
            for (int ks = 0; ks < 8; ++ks) {
                bf16x8 af = *(const bf16x8*)(oA + ks*32);
                bf16x8 bh = *(const bf16x8*)(pf_h + ks*32);
                bf16x8 bl = *(const bf16x8*)(pf_l + ks*32);
                acc = MFMA(af, bh, acc);
                acc = MFMA(af, bl, acc);
            }
            #pragma unroll
            for (int i = 0; i < 4; ++i) {
                int row = q*4 + i, col = nc + r;
                zf[row*256 + col] = acc[i] + fb2[col] + zf[row*256 + col];
            }
        }
        __syncthreads();
        do_ln(g2, b2);
        __syncthreads();
    }

    // ---- emit final z split as bf16 [A_N][4096] for the CANN GEMM ----
    {
        int row = t >> 6, col = (t & 63) * 4;
        *(bf16x4*)(Zbh + (size_t)a * 4096 + row * 256 + col) =
            *(const bf16x4*)(zbh + row * 264 + col);
        *(bf16x4*)(Zbl + (size_t)a * 4096 + row * 256 + col) =
            *(const bf16x4*)(zbl + row * 264 + col);
    }
}

// ---------------------------------------------------------------------------
// CANN q/k/v GEMM, split-bf16: C[128,4096] = Z @ W^T + b, near-fp32 accuracy.
// BM=128 (W read exactly once), BN=32, BK=64. grid (128, 3) x 256 (4 waves).
// A rows padded to 72 bf16 (144 B = 36 dwords -> 2-way LDS aliasing, free).
// y==1 (K) is stored TRANSPOSED (KT[4096][128]) so k_cann_scores reads it
// coalesced along k. fp32 values identical either way.
__global__ __launch_bounds__(256) void k_cann_gemm(
    const __bf16* __restrict__ Zh, const __bf16* __restrict__ Zl,
    const float* __restrict__ W0, const float* __restrict__ W1, const float* __restrict__ W2,
    const float* __restrict__ b0, const float* __restrict__ b1, const float* __restrict__ b2,
    float* __restrict__ C0, float* __restrict__ C1, float* __restrict__ C2)
{
    const float* W; const float* bias; float* C;
    if (blockIdx.y == 0)      { W = W0; bias = b0; C = C0; }
    else if (blockIdx.y == 1) { W = W1; bias = b1; C = C1; }
    else                      { W = W2; bias = b2; C = C2; }

    __shared__ __bf16 Ash[128 * 72];
    __shared__ __bf16 Asl[128 * 72];
    __shared__ __bf16 Bsh[32 * 72];
    __shared__ __bf16 Bsl[32 * 72];

    const int t = threadIdx.x;
    const int w = t >> 6, lane = t & 63, q = lane >> 4, r = lane & 15;
    const int n0 = blockIdx.x * 32;
    const int m0 = w * 32;
    const int br = t >> 3, bc = t & 7;

    const f32x4 zero4 = {0.f, 0.f, 0.f, 0.f};
    f32x4 acc[2][2] = {{zero4, zero4}, {zero4, zero4}};

    for (int k0 = 0; k0 < FLATD; k0 += 64) {
        #pragma unroll
        for (int l = 0; l < 4; ++l) {
            int idx = t + l * 256;
            int rr = idx >> 3, cc = idx & 7;
            *(bf16x8*)(Ash + rr*72 + cc*8) =
                *(const bf16x8*)(Zh + (size_t)rr * FLATD + k0 + cc*8);
            *(bf16x8*)(Asl + rr*72 + cc*8) =
                *(const bf16x8*)(Zl + (size_t)rr * FLATD + k0 + cc*8);
        }
        {   // stage B fp32 -> hi/lo bf16 inline
            const float4* wp = (const float4*)(W + (size_t)(n0 + br) * FLATD + k0 + bc*8);
            float4 x = wp[0], y = wp[1];
            float v[8] = {x.x, x.y, x.z, x.w, y.x, y.y, y.z, y.w};
            bf16x8 h, l;
            #pragma unroll
            for (int j = 0; j < 8; ++j) {
                __bf16 hh = (__bf16)v[j];
                h[j] = hh;
                l[j] = (__bf16)(v[j] - (float)hh);
            }
            *(bf16x8*)(Bsh + br*72 + bc*8) = h;
            *(bf16x8*)(Bsl + br*72 + bc*8) = l;
        }
        __syncthreads();
        #pragma unroll
        for (int ks = 0; ks < 2; ++ks) {
            bf16x8 a0h = *(const bf16x8*)(Ash + (m0 + r)*72      + ks*32 + q*8);
            bf16x8 a1h = *(const bf16x8*)(Ash + (m0 + 16 + r)*72 + ks*32 + q*8);
            bf16x8 a0l = *(const bf16x8*)(Asl + (m0 + r)*72      + ks*32 + q*8);
            bf16x8 a1l = *(const bf16x8*)(Asl + (m0 + 16 + r)*72 + ks*32 + q*8);
            bf16x8 g0h = *(const bf16x8*)(Bsh + r*72             + ks*32 + q*8);
            bf16x8 g1h = *(const bf16x8*)(Bsh + (16 + r)*72      + ks*32 + q*8);
            bf16x8 g0l = *(const bf16x8*)(Bsl + r*72             + ks*32 + q*8);
            bf16x8 g1l = *(const bf16x8*)(Bsl + (16 + r)*72      + ks*32 + q*8);
            acc[0][0] = MFMA(a0h, g0h, acc[0][0]);
            acc[0][0] = MFMA(a0l, g0h, acc[0][0]);
            acc[0][0] = MFMA(a0h, g0l, acc[0][0]);
            acc[0][1] = MFMA(a0h, g1h, acc[0][1]);
            acc[0][1] = MFMA(a0l, g1h, acc[0][1]);
            acc[0][1] = MFMA(a0h, g1l, acc[0][1]);
            acc[1][0] = MFMA(a1h, g0h, acc[1][0]);
            acc[1][0] = MFMA(a1l, g0h, acc[1][0]);
            acc[1][0] = MFMA(a1h, g0l, acc[1][0]);
            acc[1][1] = MFMA(a1h, g1h, acc[1][1]);
            acc[1][1] = MFMA(a1l, g1h, acc[1][1]);
            acc[1][1] = MFMA(a1h, g1l, acc[1][1]);
        }
        __syncthreads();
    }

    if (blockIdx.y == 1) {
        // KT[col][row] = acc + bias[col]   (scattered 4B stores, 16 KB/block)
        #pragma unroll
        for (int mi = 0; mi < 2; ++mi)
            #pragma unroll
            for (int ni = 0; ni < 2; ++ni)
                #pragma unroll
                for (int i = 0; i < 4; ++i) {
                    int row = m0 + mi*16 + q*4 + i;
                    int col = n0 + ni*16 + r;
                    C[(size_t)col * 128 + row] = acc[mi][ni][i] + bias[col];
                }
    } else {
        #pragma unroll
        for (int mi = 0; mi < 2; ++mi)
            #pragma unroll
            for (int ni = 0; ni < 2; ++ni)
                #pragma unroll
                for (int i = 0; i < 4; ++i) {
                    int row = m0 + mi*16 + q*4 + i;
                    int col = n0 + ni*16 + r;
                    C[(size_t)row * FLATD + col] = acc[mi][ni][i] + bias[col];
                }
    }
}

// ---------------------------------------------------------------------------
// CANN scores + softmax: P[i][j] = softmax_j(Q[i]·K[j] / 16)  (fp32).
// K supplied transposed (KT[4096][128]) -> loads coalesced across j.
// 512 threads: 4-way k-split per j for load concurrency, LDS combine.
__global__ __launch_bounds__(512) void k_cann_scores(const float* __restrict__ Q,
                              const float* __restrict__ KT,
                              float* __restrict__ P) {
    const int i = blockIdx.x;
    const int t = threadIdx.x;
    __shared__ float qrow[FLATD];
    __shared__ float part[4][128];
    __shared__ float wred[2];
    __shared__ float wsum[2];
    {
        const float4* src = (const float4*)(Q + (size_t)i * FLATD);
        float4* dst = (float4*)qrow;
        dst[t]       = src[t];
        dst[t + 512] = src[t + 512];
    }
    __syncthreads();

    const int j = t & 127, quarter = t >> 7;
    const float* kp = KT + (size_t)quarter * 1024 * 128 + j;
    const float* qp = qrow + quarter * 1024;
    float sc = 0.0f;
    #pragma unroll 8
    for (int k = 0; k < 1024; ++k) sc += qp[k] * kp[(size_t)k * 128];
    part[quarter][j] = sc;
    __syncthreads();

    float v = 0.0f;
    if (t < 128) v = (part[0][j] + part[1][j] + part[2][j] + part[3][j]) * 0.0625f;

    float mx = (t < 128) ? v : -3.4e38f;
    #pragma unroll
    for (int o = 32; o; o >>= 1) mx = fmaxf(mx, __shfl_xor(mx, o));
    if (t < 128 && (t & 63) == 0) wred[t >> 6] = mx;
    __syncthreads();
    mx = fmaxf(wred[0], wred[1]);

    float e = (t < 128) ? __expf(v - mx) : 0.0f;
    float sum = e;
    #pragma unroll
    for (int o = 32; o; o >>= 1) sum += __shfl_xor(sum, o);
    if (t < 128 && (t & 63) == 0) wsum[t >> 6] = sum;
    __syncthreads();
    sum = wsum[0] + wsum[1];

    if (t < 128) P[(size_t)i * 128 + t] = e / sum;
}

// ---------------------------------------------------------------------------
// H[i][n] = sum_j P[i][j] * V[j][n]
__global__ void k_cann_out(const float* __restrict__ P,
                           const float* __restrict__ V,
                           float* __restrict__ H) {
    const int i = blockIdx.y;
    const int n = blockIdx.x * 256 + threadIdx.x;
    __shared__ float prow[128];
    if (threadIdx.x < 128) prow[threadIdx.x] = P[(size_t)i * 128 + threadIdx.x];
    __syncthreads();
    float acc = 0.0f;
    #pragma unroll 8
    for (int j = 0; j < 128; ++j) acc += prow[j] * V[(size_t)j * FLATD + n];
    H[(size_t)i * FLATD + n] = acc;
}

// ---------------------------------------------------------------------------
extern "C" void kernel_launch(void* const* d_in, const int* in_sizes, int n_in,
                              void* d_out, int out_size, void* d_ws, size_t ws_size,
                              hipStream_t stream) {
    (void)in_sizes; (void)n_in; (void)out_size; (void)ws_size;

    const float* z      = (const float*)d_in[1];
    const float* s_wq   = (const float*)d_in[15];
    const float* s_wk   = (const float*)d_in[16];
    const float* s_wv   = (const float*)d_in[17];
    const float* s_wo   = (const float*)d_in[18];
    const float* s_bo   = (const float*)d_in[19];
    const float* s_ln1g = (const float*)d_in[20];
    const float* s_ln1b = (const float*)d_in[21];
    const float* s_fw1  = (const float*)d_in[22];
    const float* s_fb1  = (const float*)d_in[23];
    const float* s_fw2  = (const float*)d_in[24];
    const float* s_fb2  = (const float*)d_in[25];
    const float* s_ln2g = (const float*)d_in[26];
    const float* s_ln2b = (const float*)d_in[27];
    const float* q_w    = (const float*)d_in[28];
    const float* q_b    = (const float*)d_in[29];
    const float* k_w    = (const float*)d_in[30];
    const float* k_b    = (const float*)d_in[31];
    const float* v_w    = (const float*)d_in[32];
    const float* v_b    = (const float*)d_in[33];

    float* out    = (float*)d_out;
    float* Hout   = out;
    float* Zprior = out + 524288;

    // Workspace: [0,6MB) = Wh+Wl, later reused as Qb/KT/Vb (Wh/Wl dead by then)
    char* w8 = (char*)d_ws;
    __bf16* Wh  = (__bf16*)w8;                     // 6*262144 bf16 = 3 MB
    __bf16* Wl  = (__bf16*)(w8 + 3145728);         // 3 MB
    float*  Qb  = (float*)w8;                      // 2 MB (aliases Wh)
    float*  Kb  = (float*)(w8 + 2097152);          // 2 MB (stored transposed: KT[4096][128])
    float*  Vb  = (float*)(w8 + 4194304);          // 2 MB (aliases Wl tail)
    __bf16* Zbh = (__bf16*)(w8 + 6291456);         // 1 MB
    __bf16* Zbl = (__bf16*)(w8 + 7340032);         // 1 MB
    float*  Pm  = (float*)(w8 + 8388608);          // 64 KB

    k_cvt_w<<<dim3(128, 6), 256, 0, stream>>>(s_wq, s_wk, s_wv, s_wo, s_fw1, s_fw2,
                                              Wh, Wl);

    k_latent<<<A_N, 1024, 0, stream>>>(z, Wh, Wl, s_bo, s_ln1g, s_ln1b,
                                       s_fb1, s_fb2, s_ln2g, s_ln2b,
                                       Zprior, Zbh, Zbl);

    k_cann_gemm<<<dim3(FLATD / 32, 3), 256, 0, stream>>>(Zbh, Zbl, q_w, k_w, v_w,
                                                         q_b, k_b, v_b, Qb, Kb, Vb);

    k_cann_scores<<<A_N, 512, 0, stream>>>(Qb, Kb, Pm);
    k_cann_out<<<dim3(FLATD / 256, A_N), 256, 0, stream>>>(Pm, Vb, Hout);
}

// Round 2
// 521.959 us; speedup vs baseline: 1.2661x; 1.1950x over previous
//
#include <hip/hip_runtime.h>
#include <math.h>

typedef __bf16 bf16x8 __attribute__((ext_vector_type(8)));
typedef __bf16 bf16x4 __attribute__((ext_vector_type(4)));
typedef float  f32x4  __attribute__((ext_vector_type(4)));

#define MFMA(a,b,c) __builtin_amdgcn_mfma_f32_16x16x32_bf16((a),(b),(c),0,0,0)

#define A_N   128
#define LDIM  256
#define FLATD 4096

// ---------------------------------------------------------------------------
// Repack the 6 latent weight arrays (each [4][256][256] fp32) into split bf16
// (hi + lo) laid out in EXACT per-wave consumption order for k_latent:
//   stream(lp, w) = contiguous 96 KB read strictly sequentially by wave w in
//   layer lp. Per-load chunk = 1 KB (64 lanes x 16 B contiguous).
// Load index decode (96 loads per stream):
//   0..47 : qkv, ks=li/6, sub=li%6 -> m=sub>>1 (0=q,1=k,2=v), hl=sub&1
//   48..63: wo  (m=3), ks=(li-48)>>1, hl=&1
//   64..79: ff1 (m=4), ks=(li-64)>>1, hl=&1
//   80..95: ff2 (m=5), ks=(li-80)>>1, hl=&1
// Chunk (lp,w,li,lane) holds W[m][lp][w*16 + (lane&15)][ks*32 + (lane>>4)*8 + j]
// (hi if hl==0 else lo), j=0..7 -- identical values to the old strided reads.
__global__ __launch_bounds__(256) void k_cvt_w(
        const float* __restrict__ s0, const float* __restrict__ s1,
        const float* __restrict__ s2, const float* __restrict__ s3,
        const float* __restrict__ s4, const float* __restrict__ s5,
        __bf16* __restrict__ W) {
    const int g    = blockIdx.x * 256 + threadIdx.x;   // 0..393215
    const int lane = g & 63;
    const int L    = g >> 6;                           // load-group id
    const int lp   = L / 1536;
    const int rem  = L - lp * 1536;
    const int w    = rem / 96;
    const int li   = rem - w * 96;

    int m, ks, hl;
    if (li < 48)      { ks = li / 6; int sub = li - ks * 6; m = sub >> 1; hl = sub & 1; }
    else if (li < 64) { int i = li - 48; m = 3; ks = i >> 1; hl = i & 1; }
    else if (li < 80) { int i = li - 64; m = 4; ks = i >> 1; hl = i & 1; }
    else              { int i = li - 80; m = 5; ks = i >> 1; hl = i & 1; }

    const float* s;
    switch (m) {
        case 0: s = s0; break; case 1: s = s1; break; case 2: s = s2; break;
        case 3: s = s3; break; case 4: s = s4; break; default: s = s5; break;
    }
    const float* src = s + lp * 65536 + (w * 16 + (lane & 15)) * 256
                         + ks * 32 + (lane >> 4) * 8;
    float4 x = ((const float4*)src)[0], y = ((const float4*)src)[1];
    float v[8] = {x.x, x.y, x.z, x.w, y.x, y.y, y.z, y.w};
    bf16x8 o;
    #pragma unroll
    for (int j = 0; j < 8; ++j) {
        __bf16 hh = (__bf16)v[j];
        o[j] = hl ? (__bf16)(v[j] - (float)hh) : hh;
    }
    *(bf16x8*)(W + (size_t)g * 8) = o;
}

// ---------------------------------------------------------------------------
// Fused 4-layer latent transformer, split-bf16 (near-fp32) projections.
// One block per asset (16 rows x 256). 1024 threads = 16 waves.
// Weights pre-swizzled (k_cvt_w): wave w reads ONE contiguous 96 KB stream
// per layer, 1 KB per wave-load -- fully coalesced, sequential addresses
// (the old layout gathered 16 B/lane at 512-B stride: L1-set serialized).
// MFMA 16x16x32 bf16 layouts (verified m89/m91):
//   A[m=lane&15][k=(lane>>4)*8+j], B[n=lane&15][k=(lane>>4)*8+j]
//   C[m=(lane>>4)*4+reg][n=lane&15]
__global__ __launch_bounds__(1024) void k_latent(
    const float* __restrict__ z,
    const __bf16* __restrict__ Wswz,
    const float* __restrict__ boa,
    const float* __restrict__ g1a, const float* __restrict__ b1a,
    const float* __restrict__ fb1a, const float* __restrict__ fb2a,
    const float* __restrict__ g2a, const float* __restrict__ b2a,
    float* __restrict__ zprior, __bf16* __restrict__ Zbh, __bf16* __restrict__ Zbl)
{
    // LDS arena 57856 B. Aliases (barrier-guarded):
    //   Ph  aliases zbh (zb dead between qkv-proj and LN1)
    //   ob  aliases Qh + first 256 B of Kh (dead after scores)
    __shared__ __align__(16) char arena[57856];
    float*  zf  = (float*)arena;                    // [16][256] f32 residual
    __bf16* zbh = (__bf16*)(arena + 16384);         // [16][264]
    __bf16* zbl = (__bf16*)(arena + 24832);         // [16][264]
    __bf16* Ph  = (__bf16*)(arena + 16384);         // [8][16][32] (k-pad 0)
    __bf16* Qh  = (__bf16*)(arena + 33280);         // [8][16][32]
    __bf16* ob  = Qh;                               // [16][264]
    __bf16* Kh  = (__bf16*)(arena + 41472);         // [8][16][32]
    __bf16* Vt  = (__bf16*)(arena + 49664);         // [8][32][16] V^T compact

    const int a    = blockIdx.x;
    const int t    = threadIdx.x;
    const int w    = t >> 6;          // 0..15
    const int lane = t & 63;
    const int q    = lane >> 4;
    const int r    = lane & 15;
    const int nc   = w * 16;          // GEMM output col base for this wave
    const int head = w >> 1;          // attention head for qkv store
    const int hc   = (w & 1) * 16;    // col-half within head

    // ---- load z -> zf, zbh/zbl; emit z_prior (4 floats/thread) ----
    {
        int row = t >> 6, col = (t & 63) * 4;
        const float4 x = *(const float4*)(z + (size_t)a * 4096 + row * 256 + col);
        *(float4*)(zprior + (size_t)a * 4096 + row * 256 + col) = x;
        float v[4] = {x.x, x.y, x.z, x.w};
        float*  zr = zf  + row * 256 + col;
        __bf16* zh = zbh + row * 264 + col;
        __bf16* zl = zbl + row * 264 + col;
        #pragma unroll
        for (int j = 0; j < 4; ++j) {
            zr[j] = v[j];
            __bf16 hh = (__bf16)v[j];
            zh[j] = hh;
            zl[j] = (__bf16)(v[j] - (float)hh);
        }
    }
    __syncthreads();

    // wave w handles row w (64 lanes x 4 cols)
    auto do_ln = [&](const float* g, const float* bb) {
        int col = lane * 4;
        float* zr = zf + w * 256 + col;
        float4 v4 = *(const float4*)zr;
        float v[4] = {v4.x, v4.y, v4.z, v4.w};
        float s1 = 0.f, s2 = 0.f;
        #pragma unroll
        for (int j = 0; j < 4; ++j) { s1 += v[j]; s2 += v[j]*v[j]; }
        #pragma unroll
        for (int o = 1; o <= 32; o <<= 1) {
            s1 += __shfl_xor(s1, o);
            s2 += __shfl_xor(s2, o);
        }
        float mean = s1 * (1.0f/256.0f);
        float var  = s2 * (1.0f/256.0f) - mean * mean;
        float inv  = rsqrtf(var + 1e-5f);
        float4 g4 = *(const float4*)(g + col);
        float4 b4 = *(const float4*)(bb + col);
        float gg[4] = {g4.x, g4.y, g4.z, g4.w};
        float bbv[4] = {b4.x, b4.y, b4.z, b4.w};
        __bf16* zh = zbh + w * 264 + col;
        __bf16* zl = zbl + w * 264 + col;
        float y[4];
        #pragma unroll
        for (int j = 0; j < 4; ++j) {
            y[j] = (v[j] - mean) * inv * gg[j] + bbv[j];
            __bf16 hh = (__bf16)y[j];
            zh[j] = hh;
            zl[j] = (__bf16)(y[j] - (float)hh);
        }
        *(float4*)zr = (float4){y[0], y[1], y[2], y[3]};
    };

    const f32x4 zero4 = {0.f, 0.f, 0.f, 0.f};
    bf16x8 zer8;
    #pragma unroll
    for (int j = 0; j < 8; ++j) zer8[j] = (__bf16)0.0f;

    for (int lp = 0; lp < 4; ++lp) {
        const float* bo  = boa  + lp*256;
        const float* g1  = g1a  + lp*256; const float* b1 = b1a + lp*256;
        const float* fb1 = fb1a + lp*256; const float* fb2 = fb2a + lp*256;
        const float* g2  = g2a  + lp*256; const float* b2 = b2a + lp*256;

        // per-wave contiguous weight stream (see k_cvt_w layout comment)
        const __bf16* wsl = Wswz + (size_t)(lp * 16 + w) * 49152 + (size_t)lane * 8;
        #define WCHUNK(idx) (*(const bf16x8*)(wsl + (idx) * 512))

        const __bf16* zA_h = zbh + r * 264 + q * 8;          // A frag base
        const __bf16* zA_l = zbl + r * 264 + q * 8;
        const __bf16* oA   = ob  + r * 264 + q * 8;

        // ---- q,k,v projections: 3 interleaved split-product chains ----
        {
            f32x4 aq = zero4, ak = zero4, av = zero4;
            #pragma unroll
            for (int ks = 0; ks < 8; ++ks) {
                bf16x8 afh = *(const bf16x8*)(zA_h + ks*32);
                bf16x8 afl = *(const bf16x8*)(zA_l + ks*32);
                bf16x8 qh = WCHUNK(ks*6 + 0);
                bf16x8 ql = WCHUNK(ks*6 + 1);
                bf16x8 kh = WCHUNK(ks*6 + 2);
                bf16x8 kl = WCHUNK(ks*6 + 3);
                bf16x8 vh = WCHUNK(ks*6 + 4);
                bf16x8 vl = WCHUNK(ks*6 + 5);
                aq = MFMA(afh, qh, aq); aq = MFMA(afl, qh, aq); aq = MFMA(afh, ql, aq);
                ak = MFMA(afh, kh, ak); ak = MFMA(afl, kh, ak); ak = MFMA(afh, kl, ak);
                av = MFMA(afh, vh, av); av = MFMA(afl, vh, av); av = MFMA(afh, vl, av);
            }
            #pragma unroll
            for (int i = 0; i < 4; ++i) {
                int m = q*4 + i;
                Qh[(head*16 + m)*32 + hc + r] = (__bf16)aq[i];
                Kh[(head*16 + m)*32 + hc + r] = (__bf16)ak[i];
                Vt[(head*32 + hc + r)*16 + m] = (__bf16)av[i];
            }
        }
        __syncthreads();   // Qh/Kh/Vt visible; zb reads done (Ph may alias)

        // ---- scores + softmax, head w per wave (waves 0..7 only) ----
        if (w < 8) {
            bf16x8 qa = *(const bf16x8*)(Qh + (w*16 + r)*32 + q*8);
            bf16x8 ka = *(const bf16x8*)(Kh + (w*16 + r)*32 + q*8);
            f32x4 s = MFMA(qa, ka, zero4);   // S[i=q*4+reg][j=r], K = hd = 32
            #pragma unroll
            for (int i = 0; i < 4; ++i) {
                float sc = s[i] * 0.17677669529663687f;
                float mx = sc;
                #pragma unroll
                for (int o = 1; o <= 8; o <<= 1) mx = fmaxf(mx, __shfl_xor(mx, o, 16));
                float e = __expf(sc - mx);
                float sm = e;
                #pragma unroll
                for (int o = 1; o <= 8; o <<= 1) sm += __shfl_xor(sm, o, 16);
                Ph[(w*16 + q*4 + i)*32 + r]      = (__bf16)(e / sm);
                Ph[(w*16 + q*4 + i)*32 + 16 + r] = (__bf16)0.0f;   // k-pad
            }
        }
        __syncthreads();   // all Qh/Kh reads done (ob may alias)

        // ---- O = P @ V. 16 waves: head = w&7, d-half = w>>3 ----
        {
            int ph = w & 7, vnt = w >> 3;
            bf16x8 pa = *(const bf16x8*)(Ph + (ph*16 + r)*32 + q*8);
            bf16x8 vb = (q < 2)
                ? *(const bf16x8*)(Vt + (ph*32 + vnt*16 + r)*16 + q*8) : zer8;
            f32x4 o = MFMA(pa, vb, zero4);   // O[i=q*4+reg][d=vnt*16+r]
            #pragma unroll
            for (int i = 0; i < 4; ++i)
                ob[(q*4 + i)*264 + ph*32 + vnt*16 + r] = (__bf16)o[i];
        }
        __syncthreads();

        // ---- wo projection (A=ob single, split B) + bias + residual ----
        {
            f32x4 acc = zero4;
            #pragma unroll
            for (int ks = 0; ks < 8; ++ks) {
                bf16x8 af = *(const bf16x8*)(oA + ks*32);
                bf16x8 bh = WCHUNK(48 + ks*2);
                bf16x8 bl = WCHUNK(49 + ks*2);
                acc = MFMA(af, bh, acc);
                acc = MFMA(af, bl, acc);
            }
            #pragma unroll
            for (int i = 0; i < 4; ++i) {
                int row = q*4 + i, col = nc + r;
                zf[row*256 + col] = acc[i] + bo[col] + zf[row*256 + col];
            }
        }
        __syncthreads();
        do_ln(g1, b1);
        __syncthreads();

        // ---- FF1: relu(z @ f1^T + fb1) -> ob (split A x split B) ----
        {
            f32x4 acc = zero4;
            #pragma unroll
            for (int ks = 0; ks < 8; ++ks) {
                bf16x8 afh = *(const bf16x8*)(zA_h + ks*32);
                bf16x8 afl = *(const bf16x8*)(zA_l + ks*32);
                bf16x8 bh  = WCHUNK(64 + ks*2);
                bf16x8 bl  = WCHUNK(65 + ks*2);
                acc = MFMA(afh, bh, acc);
                acc = MFMA(afl, bh, acc);
                acc = MFMA(afh, bl, acc);
            }
            #pragma unroll
            for (int i = 0; i < 4; ++i) {
                int row = q*4 + i, col = nc + r;
                ob[row*264 + col] = (__bf16)fmaxf(acc[i] + fb1[col], 0.0f);
            }
        }
        __syncthreads();

        // ---- FF2 (A=ob single, split B) + bias + residual ----
        {
            f32x4 acc = zero4;
            #pragma unroll
            for (int ks = 0; ks < 8; ++ks) {
                bf16x8 af = *(const bf16x8*)(oA + ks*32);
                bf16x8 bh = WCHUNK(80 + ks*2);
                bf16x8 bl = WCHUNK(81 + ks*2);
                acc = MFMA(af, bh, acc);
                acc = MFMA(af, bl, acc);
            }
            #pragma unroll
            for (int i = 0; i < 4; ++i) {
                int row = q*4 + i, col = nc + r;
                zf[row*256 + col] = acc[i] + fb2[col] + zf[row*256 + col];
            }
        }
        __syncthreads();
        do_ln(g2, b2);
        __syncthreads();
        #undef WCHUNK
    }

    // ---- emit final z split as bf16 [A_N][4096] for the CANN GEMM ----
    {
        int row = t >> 6, col = (t & 63) * 4;
        *(bf16x4*)(Zbh + (size_t)a * 4096 + row * 256 + col) =
            *(const bf16x4*)(zbh + row * 264 + col);
        *(bf16x4*)(Zbl + (size_t)a * 4096 + row * 256 + col) =
            *(const bf16x4*)(zbl + row * 264 + col);
    }
}

// ---------------------------------------------------------------------------
// CANN q/k/v GEMM, split-bf16: C[128,4096] = Z @ W^T + b, near-fp32 accuracy.
// BM=128 (W read exactly once), BN=32, BK=64. grid (128, 3) x 256 (4 waves).
// A rows padded to 72 bf16 (144 B = 36 dwords -> 2-way LDS aliasing, free).
// y==1 (K) is stored TRANSPOSED (KT[4096][128]) so k_cann_scores reads it
// coalesced along k. fp32 values identical either way.
__global__ __launch_bounds__(256) void k_cann_gemm(
    const __bf16* __restrict__ Zh, const __bf16* __restrict__ Zl,
    const float* __restrict__ W0, const float* __restrict__ W1, const float* __restrict__ W2,
    const float* __restrict__ b0, const float* __restrict__ b1, const float* __restrict__ b2,
    float* __restrict__ C0, float* __restrict__ C1, float* __restrict__ C2)
{
    const float* W; const float* bias; float* C;
    if (blockIdx.y == 0)      { W = W0; bias = b0; C = C0; }
    else if (blockIdx.y == 1) { W = W1; bias = b1; C = C1; }
    else                      { W = W2; bias = b2; C = C2; }

    __shared__ __bf16 Ash[128 * 72];
    __shared__ __bf16 Asl[128 * 72];
    __shared__ __bf16 Bsh[32 * 72];
    __shared__ __bf16 Bsl[32 * 72];

    const int t = threadIdx.x;
    const int w = t >> 6, lane = t & 63, q = lane >> 4, r = lane & 15;
    const int n0 = blockIdx.x * 32;
    const int m0 = w * 32;
    const int br = t >> 3, bc = t & 7;

    const f32x4 zero4 = {0.f, 0.f, 0.f, 0.f};
    f32x4 acc[2][2] = {{zero4, zero4}, {zero4, zero4}};

    for (int k0 = 0; k0 < FLATD; k0 += 64) {
        #pragma unroll
        for (int l = 0; l < 4; ++l) {
            int idx = t + l * 256;
            int rr = idx >> 3, cc = idx & 7;
            *(bf16x8*)(Ash + rr*72 + cc*8) =
                *(const bf16x8*)(Zh + (size_t)rr * FLATD + k0 + cc*8);
            *(bf16x8*)(Asl + rr*72 + cc*8) =
                *(const bf16x8*)(Zl + (size_t)rr * FLATD + k0 + cc*8);
        }
        {   // stage B fp32 -> hi/lo bf16 inline
            const float4* wp = (const float4*)(W + (size_t)(n0 + br) * FLATD + k0 + bc*8);
            float4 x = wp[0], y = wp[1];
            float v[8] = {x.x, x.y, x.z, x.w, y.x, y.y, y.z, y.w};
            bf16x8 h, l;
            #pragma unroll
            for (int j = 0; j < 8; ++j) {
                __bf16 hh = (__bf16)v[j];
                h[j] = hh;
                l[j] = (__bf16)(v[j] - (float)hh);
            }
            *(bf16x8*)(Bsh + br*72 + bc*8) = h;
            *(bf16x8*)(Bsl + br*72 + bc*8) = l;
        }
        __syncthreads();
        #pragma unroll
        for (int ks = 0; ks < 2; ++ks) {
            bf16x8 a0h = *(const bf16x8*)(Ash + (m0 + r)*72      + ks*32 + q*8);
            bf16x8 a1h = *(const bf16x8*)(Ash + (m0 + 16 + r)*72 + ks*32 + q*8);
            bf16x8 a0l = *(const bf16x8*)(Asl + (m0 + r)*72      + ks*32 + q*8);
            bf16x8 a1l = *(const bf16x8*)(Asl + (m0 + 16 + r)*72 + ks*32 + q*8);
            bf16x8 g0h = *(const bf16x8*)(Bsh + r*72             + ks*32 + q*8);
            bf16x8 g1h = *(const bf16x8*)(Bsh + (16 + r)*72      + ks*32 + q*8);
            bf16x8 g0l = *(const bf16x8*)(Bsl + r*72             + ks*32 + q*8);
            bf16x8 g1l = *(const bf16x8*)(Bsl + (16 + r)*72      + ks*32 + q*8);
            acc[0][0] = MFMA(a0h, g0h, acc[0][0]);
            acc[0][0] = MFMA(a0l, g0h, acc[0][0]);
            acc[0][0] = MFMA(a0h, g0l, acc[0][0]);
            acc[0][1] = MFMA(a0h, g1h, acc[0][1]);
            acc[0][1] = MFMA(a0l, g1h, acc[0][1]);
            acc[0][1] = MFMA(a0h, g1l, acc[0][1]);
            acc[1][0] = MFMA(a1h, g0h, acc[1][0]);
            acc[1][0] = MFMA(a1l, g0h, acc[1][0]);
            acc[1][0] = MFMA(a1h, g0l, acc[1][0]);
            acc[1][1] = MFMA(a1h, g1h, acc[1][1]);
            acc[1][1] = MFMA(a1l, g1h, acc[1][1]);
            acc[1][1] = MFMA(a1h, g1l, acc[1][1]);
        }
        __syncthreads();
    }

    if (blockIdx.y == 1) {
        // KT[col][row] = acc + bias[col]   (scattered 4B stores, 16 KB/block)
        #pragma unroll
        for (int mi = 0; mi < 2; ++mi)
            #pragma unroll
            for (int ni = 0; ni < 2; ++ni)
                #pragma unroll
                for (int i = 0; i < 4; ++i) {
                    int row = m0 + mi*16 + q*4 + i;
                    int col = n0 + ni*16 + r;
                    C[(size_t)col * 128 + row] = acc[mi][ni][i] + bias[col];
                }
    } else {
        #pragma unroll
        for (int mi = 0; mi < 2; ++mi)
            #pragma unroll
            for (int ni = 0; ni < 2; ++ni)
                #pragma unroll
                for (int i = 0; i < 4; ++i) {
                    int row = m0 + mi*16 + q*4 + i;
                    int col = n0 + ni*16 + r;
                    C[(size_t)row * FLATD + col] = acc[mi][ni][i] + bias[col];
                }
    }
}

// ---------------------------------------------------------------------------
// CANN scores + softmax, 2 Q-rows per block (amortizes the KT stream):
// P[i][j] = softmax_j(Q[i]·K[j] / 16). KT is [4096][128] (k-major).
// 512 threads: j = t&127, 4-way k-split (t>>7). Q rows staged in LDS.
__global__ __launch_bounds__(512) void k_cann_scores(const float* __restrict__ Q,
                              const float* __restrict__ KT,
                              float* __restrict__ P) {
    const int i0 = blockIdx.x * 2;
    const int t  = threadIdx.x;
    __shared__ float qs[2][FLATD];
    __shared__ float part[4][2][128];
    __shared__ float wred[2][2];
    __shared__ float wsum[2][2];
    {
        const float4* src = (const float4*)(Q + (size_t)i0 * FLATD);
        float4* dst = (float4*)qs;
        #pragma unroll
        for (int u = 0; u < 4; ++u) dst[t + u * 512] = src[t + u * 512];
    }
    __syncthreads();

    const int j = t & 127, ksub = t >> 7;
    const float* kp = KT + (size_t)(ksub * 1024) * 128 + j;
    const float* q0 = qs[0] + ksub * 1024;
    const float* q1 = qs[1] + ksub * 1024;
    float a0 = 0.0f, a1 = 0.0f;
    #pragma unroll 8
    for (int k = 0; k < 1024; ++k) {
        float kv = kp[(size_t)k * 128];
        a0 += q0[k] * kv;
        a1 += q1[k] * kv;
    }
    part[ksub][0][j] = a0;
    part[ksub][1][j] = a1;
    __syncthreads();

    // t < 256: i = t>>7, j = t&127; softmax per row across 2 waves
    float v = 0.0f, e = 0.0f;
    const int i = t >> 7;
    if (t < 256)
        v = (part[0][i][j] + part[1][i][j] + part[2][i][j] + part[3][i][j]) * 0.0625f;

    float mx = (t < 256) ? v : -3.4e38f;
    #pragma unroll
    for (int o = 32; o; o >>= 1) mx = fmaxf(mx, __shfl_xor(mx, o));
    if (t < 256 && (j & 63) == 0) wred[i][j >> 6] = mx;
    __syncthreads();
    if (t < 256) {
        mx = fmaxf(wred[i][0], wred[i][1]);
        e = __expf(v - mx);
    }
    float sum = e;
    #pragma unroll
    for (int o = 32; o; o >>= 1) sum += __shfl_xor(sum, o);
    if (t < 256 && (j & 63) == 0) wsum[i][j >> 6] = sum;
    __syncthreads();
    if (t < 256) {
        sum = wsum[i][0] + wsum[i][1];
        P[(size_t)(i0 + i) * 128 + j] = e / sum;
    }
}

// ---------------------------------------------------------------------------
// H[i][n] = sum_j P[i][j] * V[j][n]. 8 rows x 1024-col tile per block:
// V traffic 268 MB -> 32 MB. P staged transposed (ps[j][i]) for b128 reads.
__global__ __launch_bounds__(256) void k_cann_out(const float* __restrict__ P,
                           const float* __restrict__ V,
                           float* __restrict__ H) {
    const int i0 = blockIdx.y * 8;
    const int t  = threadIdx.x;
    const int nb = blockIdx.x * 1024 + t * 4;
    __shared__ float ps[128][8];
    #pragma unroll
    for (int u = 0; u < 4; ++u) {
        int e = t + u * 256;            // 0..1023
        int i = e >> 7, j = e & 127;
        ps[j][i] = P[(size_t)(i0 + i) * 128 + j];
    }
    __syncthreads();

    f32x4 acc[8];
    #pragma unroll
    for (int i = 0; i < 8; ++i) acc[i] = (f32x4){0.f, 0.f, 0.f, 0.f};

    for (int j = 0; j < 128; ++j) {
        float4 vv = *(const float4*)(V + (size_t)j * FLATD + nb);
        f32x4 v4 = {vv.x, vv.y, vv.z, vv.w};
        float4 pa = *(const float4*)&ps[j][0];
        float4 pb = *(const float4*)&ps[j][4];
        acc[0] += pa.x * v4; acc[1] += pa.y * v4;
        acc[2] += pa.z * v4; acc[3] += pa.w * v4;
        acc[4] += pb.x * v4; acc[5] += pb.y * v4;
        acc[6] += pb.z * v4; acc[7] += pb.w * v4;
    }
    #pragma unroll
    for (int i = 0; i < 8; ++i) {
        f32x4 a = acc[i];
        *(float4*)(H + (size_t)(i0 + i) * FLATD + nb) =
            (float4){a[0], a[1], a[2], a[3]};
    }
}

// ---------------------------------------------------------------------------
extern "C" void kernel_launch(void* const* d_in, const int* in_sizes, int n_in,
                              void* d_out, int out_size, void* d_ws, size_t ws_size,
                              hipStream_t stream) {
    (void)in_sizes; (void)n_in; (void)out_size; (void)ws_size;

    const float* z      = (const float*)d_in[1];
    const float* s_wq   = (const float*)d_in[15];
    const float* s_wk   = (const float*)d_in[16];
    const float* s_wv   = (const float*)d_in[17];
    const float* s_wo   = (const float*)d_in[18];
    const float* s_bo   = (const float*)d_in[19];
    const float* s_ln1g = (const float*)d_in[20];
    const float* s_ln1b = (const float*)d_in[21];
    const float* s_fw1  = (const float*)d_in[22];
    const float* s_fb1  = (const float*)d_in[23];
    const float* s_fw2  = (const float*)d_in[24];
    const float* s_fb2  = (const float*)d_in[25];
    const float* s_ln2g = (const float*)d_in[26];
    const float* s_ln2b = (const float*)d_in[27];
    const float* q_w    = (const float*)d_in[28];
    const float* q_b    = (const float*)d_in[29];
    const float* k_w    = (const float*)d_in[30];
    const float* k_b    = (const float*)d_in[31];
    const float* v_w    = (const float*)d_in[32];
    const float* v_b    = (const float*)d_in[33];

    float* out    = (float*)d_out;
    float* Hout   = out;
    float* Zprior = out + 524288;

    // Workspace: [0,6MB) = Wswz, later reused as Qb/KT/Vb (Wswz dead by then)
    char* w8 = (char*)d_ws;
    __bf16* Wswz = (__bf16*)w8;                    // 6.29 MB swizzled weights
    float*  Qb  = (float*)w8;                      // 2 MB (aliases Wswz)
    float*  Kb  = (float*)(w8 + 2097152);          // 2 MB (KT[4096][128])
    float*  Vb  = (float*)(w8 + 4194304);          // 2 MB
    __bf16* Zbh = (__bf16*)(w8 + 6291456);         // 1 MB
    __bf16* Zbl = (__bf16*)(w8 + 7340032);         // 1 MB
    float*  Pm  = (float*)(w8 + 8388608);          // 64 KB

    k_cvt_w<<<1536, 256, 0, stream>>>(s_wq, s_wk, s_wv, s_wo, s_fw1, s_fw2, Wswz);

    k_latent<<<A_N, 1024, 0, stream>>>(z, Wswz, s_bo, s_ln1g, s_ln1b,
                                       s_fb1, s_fb2, s_ln2g, s_ln2b,
                                       Zprior, Zbh, Zbl);

    k_cann_gemm<<<dim3(FLATD / 32, 3), 256, 0, stream>>>(Zbh, Zbl, q_w, k_w, v_w,
                                                         q_b, k_b, v_b, Qb, Kb, Vb);

    k_cann_scores<<<A_N / 2, 512, 0, stream>>>(Qb, Kb, Pm);
    k_cann_out<<<dim3(4, 16), 256, 0, stream>>>(Pm, Vb, Hout);
}

// Round 3
// 519.874 us; speedup vs baseline: 1.2712x; 1.0040x over previous
//
#include <hip/hip_runtime.h>
#include <math.h>

typedef __bf16 bf16x8 __attribute__((ext_vector_type(8)));
typedef __bf16 bf16x4 __attribute__((ext_vector_type(4)));
typedef float  f32x4  __attribute__((ext_vector_type(4)));

#define MFMA(a,b,c) __builtin_amdgcn_mfma_f32_16x16x32_bf16((a),(b),(c),0,0,0)

#define A_N   128
#define LDIM  256
#define FLATD 4096

// ---------------------------------------------------------------------------
// Repack the 6 latent weight arrays (each [4][256][256] fp32) into split bf16
// (hi + lo) laid out in EXACT per-wave consumption order for k_latent:
//   stream(lp, w) = contiguous 96 KB read strictly sequentially by wave w in
//   layer lp. Per-load chunk = 1 KB (64 lanes x 16 B contiguous).
// Load index decode (96 loads per stream):
//   0..47 : qkv, ks=li/6, sub=li%6 -> m=sub>>1 (0=q,1=k,2=v), hl=sub&1
//   48..63: wo  (m=3), ks=(li-48)>>1, hl=&1
//   64..79: ff1 (m=4), ks=(li-64)>>1, hl=&1
//   80..95: ff2 (m=5), ks=(li-80)>>1, hl=&1
// Chunk (lp,w,li,lane) holds W[m][lp][w*16 + (lane&15)][ks*32 + (lane>>4)*8 + j]
// (hi if hl==0 else lo), j=0..7 -- identical values to the old strided reads.
__global__ __launch_bounds__(256) void k_cvt_w(
        const float* __restrict__ s0, const float* __restrict__ s1,
        const float* __restrict__ s2, const float* __restrict__ s3,
        const float* __restrict__ s4, const float* __restrict__ s5,
        __bf16* __restrict__ W) {
    const int g    = blockIdx.x * 256 + threadIdx.x;   // 0..393215
    const int lane = g & 63;
    const int L    = g >> 6;                           // load-group id
    const int lp   = L / 1536;
    const int rem  = L - lp * 1536;
    const int w    = rem / 96;
    const int li   = rem - w * 96;

    int m, ks, hl;
    if (li < 48)      { ks = li / 6; int sub = li - ks * 6; m = sub >> 1; hl = sub & 1; }
    else if (li < 64) { int i = li - 48; m = 3; ks = i >> 1; hl = i & 1; }
    else if (li < 80) { int i = li - 64; m = 4; ks = i >> 1; hl = i & 1; }
    else              { int i = li - 80; m = 5; ks = i >> 1; hl = i & 1; }

    const float* s;
    switch (m) {
        case 0: s = s0; break; case 1: s = s1; break; case 2: s = s2; break;
        case 3: s = s3; break; case 4: s = s4; break; default: s = s5; break;
    }
    const float* src = s + lp * 65536 + (w * 16 + (lane & 15)) * 256
                         + ks * 32 + (lane >> 4) * 8;
    float4 x = ((const float4*)src)[0], y = ((const float4*)src)[1];
    float v[8] = {x.x, x.y, x.z, x.w, y.x, y.y, y.z, y.w};
    bf16x8 o;
    #pragma unroll
    for (int j = 0; j < 8; ++j) {
        __bf16 hh = (__bf16)v[j];
        o[j] = hl ? (__bf16)(v[j] - (float)hh) : hh;
    }
    *(bf16x8*)(W + (size_t)g * 8) = o;
}

// ---------------------------------------------------------------------------
// Fused 4-layer latent transformer, split-bf16 (near-fp32) projections.
// One block per asset (16 rows x 256). 1024 threads = 16 waves.
// Weights pre-swizzled (k_cvt_w): wave w reads ONE contiguous 96 KB stream
// per layer, 1 KB per wave-load -- fully coalesced, sequential addresses.
// MFMA 16x16x32 bf16 layouts (verified m89/m91):
//   A[m=lane&15][k=(lane>>4)*8+j], B[n=lane&15][k=(lane>>4)*8+j]
//   C[m=(lane>>4)*4+reg][n=lane&15]
__global__ __launch_bounds__(1024) void k_latent(
    const float* __restrict__ z,
    const __bf16* __restrict__ Wswz,
    const float* __restrict__ boa,
    const float* __restrict__ g1a, const float* __restrict__ b1a,
    const float* __restrict__ fb1a, const float* __restrict__ fb2a,
    const float* __restrict__ g2a, const float* __restrict__ b2a,
    float* __restrict__ zprior, __bf16* __restrict__ Zbh, __bf16* __restrict__ Zbl)
{
    // LDS arena 57856 B. Aliases (barrier-guarded):
    //   Ph  aliases zbh (zb dead between qkv-proj and LN1)
    //   ob  aliases Qh + first 256 B of Kh (dead after scores)
    __shared__ __align__(16) char arena[57856];
    float*  zf  = (float*)arena;                    // [16][256] f32 residual
    __bf16* zbh = (__bf16*)(arena + 16384);         // [16][264]
    __bf16* zbl = (__bf16*)(arena + 24832);         // [16][264]
    __bf16* Ph  = (__bf16*)(arena + 16384);         // [8][16][32] (k-pad 0)
    __bf16* Qh  = (__bf16*)(arena + 33280);         // [8][16][32]
    __bf16* ob  = Qh;                               // [16][264]
    __bf16* Kh  = (__bf16*)(arena + 41472);         // [8][16][32]
    __bf16* Vt  = (__bf16*)(arena + 49664);         // [8][32][16] V^T compact

    const int a    = blockIdx.x;
    const int t    = threadIdx.x;
    const int w    = t >> 6;          // 0..15
    const int lane = t & 63;
    const int q    = lane >> 4;
    const int r    = lane & 15;
    const int nc   = w * 16;          // GEMM output col base for this wave
    const int head = w >> 1;          // attention head for qkv store
    const int hc   = (w & 1) * 16;    // col-half within head

    // ---- load z -> zf, zbh/zbl; emit z_prior (4 floats/thread) ----
    {
        int row = t >> 6, col = (t & 63) * 4;
        const float4 x = *(const float4*)(z + (size_t)a * 4096 + row * 256 + col);
        *(float4*)(zprior + (size_t)a * 4096 + row * 256 + col) = x;
        float v[4] = {x.x, x.y, x.z, x.w};
        float*  zr = zf  + row * 256 + col;
        __bf16* zh = zbh + row * 264 + col;
        __bf16* zl = zbl + row * 264 + col;
        #pragma unroll
        for (int j = 0; j < 4; ++j) {
            zr[j] = v[j];
            __bf16 hh = (__bf16)v[j];
            zh[j] = hh;
            zl[j] = (__bf16)(v[j] - (float)hh);
        }
    }
    __syncthreads();

    // wave w handles row w (64 lanes x 4 cols)
    auto do_ln = [&](const float* g, const float* bb) {
        int col = lane * 4;
        float* zr = zf + w * 256 + col;
        float4 v4 = *(const float4*)zr;
        float v[4] = {v4.x, v4.y, v4.z, v4.w};
        float s1 = 0.f, s2 = 0.f;
        #pragma unroll
        for (int j = 0; j < 4; ++j) { s1 += v[j]; s2 += v[j]*v[j]; }
        #pragma unroll
        for (int o = 1; o <= 32; o <<= 1) {
            s1 += __shfl_xor(s1, o);
            s2 += __shfl_xor(s2, o);
        }
        float mean = s1 * (1.0f/256.0f);
        float var  = s2 * (1.0f/256.0f) - mean * mean;
        float inv  = rsqrtf(var + 1e-5f);
        float4 g4 = *(const float4*)(g + col);
        float4 b4 = *(const float4*)(bb + col);
        float gg[4] = {g4.x, g4.y, g4.z, g4.w};
        float bbv[4] = {b4.x, b4.y, b4.z, b4.w};
        __bf16* zh = zbh + w * 264 + col;
        __bf16* zl = zbl + w * 264 + col;
        float y[4];
        #pragma unroll
        for (int j = 0; j < 4; ++j) {
            y[j] = (v[j] - mean) * inv * gg[j] + bbv[j];
            __bf16 hh = (__bf16)y[j];
            zh[j] = hh;
            zl[j] = (__bf16)(y[j] - (float)hh);
        }
        *(float4*)zr = (float4){y[0], y[1], y[2], y[3]};
    };

    const f32x4 zero4 = {0.f, 0.f, 0.f, 0.f};
    bf16x8 zer8;
    #pragma unroll
    for (int j = 0; j < 8; ++j) zer8[j] = (__bf16)0.0f;

    for (int lp = 0; lp < 4; ++lp) {
        const float* bo  = boa  + lp*256;
        const float* g1  = g1a  + lp*256; const float* b1 = b1a + lp*256;
        const float* fb1 = fb1a + lp*256; const float* fb2 = fb2a + lp*256;
        const float* g2  = g2a  + lp*256; const float* b2 = b2a + lp*256;

        // per-wave contiguous weight stream (see k_cvt_w layout comment)
        const __bf16* wsl = Wswz + (size_t)(lp * 16 + w) * 49152 + (size_t)lane * 8;
        #define WCHUNK(idx) (*(const bf16x8*)(wsl + (idx) * 512))

        const __bf16* zA_h = zbh + r * 264 + q * 8;          // A frag base
        const __bf16* zA_l = zbl + r * 264 + q * 8;
        const __bf16* oA   = ob  + r * 264 + q * 8;

        // ---- q,k,v projections: 3 interleaved split-product chains ----
        {
            f32x4 aq = zero4, ak = zero4, av = zero4;
            #pragma unroll
            for (int ks = 0; ks < 8; ++ks) {
                bf16x8 afh = *(const bf16x8*)(zA_h + ks*32);
                bf16x8 afl = *(const bf16x8*)(zA_l + ks*32);
                bf16x8 qh = WCHUNK(ks*6 + 0);
                bf16x8 ql = WCHUNK(ks*6 + 1);
                bf16x8 kh = WCHUNK(ks*6 + 2);
                bf16x8 kl = WCHUNK(ks*6 + 3);
                bf16x8 vh = WCHUNK(ks*6 + 4);
                bf16x8 vl = WCHUNK(ks*6 + 5);
                aq = MFMA(afh, qh, aq); aq = MFMA(afl, qh, aq); aq = MFMA(afh, ql, aq);
                ak = MFMA(afh, kh, ak); ak = MFMA(afl, kh, ak); ak = MFMA(afh, kl, ak);
                av = MFMA(afh, vh, av); av = MFMA(afl, vh, av); av = MFMA(afh, vl, av);
            }
            #pragma unroll
            for (int i = 0; i < 4; ++i) {
                int m = q*4 + i;
                Qh[(head*16 + m)*32 + hc + r] = (__bf16)aq[i];
                Kh[(head*16 + m)*32 + hc + r] = (__bf16)ak[i];
                Vt[(head*32 + hc + r)*16 + m] = (__bf16)av[i];
            }
        }
        __syncthreads();   // Qh/Kh/Vt visible; zb reads done (Ph may alias)

        // ---- scores + softmax, head w per wave (waves 0..7 only) ----
        if (w < 8) {
            bf16x8 qa = *(const bf16x8*)(Qh + (w*16 + r)*32 + q*8);
            bf16x8 ka = *(const bf16x8*)(Kh + (w*16 + r)*32 + q*8);
            f32x4 s = MFMA(qa, ka, zero4);   // S[i=q*4+reg][j=r], K = hd = 32
            #pragma unroll
            for (int i = 0; i < 4; ++i) {
                float sc = s[i] * 0.17677669529663687f;
                float mx = sc;
                #pragma unroll
                for (int o = 1; o <= 8; o <<= 1) mx = fmaxf(mx, __shfl_xor(mx, o, 16));
                float e = __expf(sc - mx);
                float sm = e;
                #pragma unroll
                for (int o = 1; o <= 8; o <<= 1) sm += __shfl_xor(sm, o, 16);
                Ph[(w*16 + q*4 + i)*32 + r]      = (__bf16)(e / sm);
                Ph[(w*16 + q*4 + i)*32 + 16 + r] = (__bf16)0.0f;   // k-pad
            }
        }
        __syncthreads();   // all Qh/Kh reads done (ob may alias)

        // ---- O = P @ V. 16 waves: head = w&7, d-half = w>>3 ----
        {
            int ph = w & 7, vnt = w >> 3;
            bf16x8 pa = *(const bf16x8*)(Ph + (ph*16 + r)*32 + q*8);
            bf16x8 vb = (q < 2)
                ? *(const bf16x8*)(Vt + (ph*32 + vnt*16 + r)*16 + q*8) : zer8;
            f32x4 o = MFMA(pa, vb, zero4);   // O[i=q*4+reg][d=vnt*16+r]
            #pragma unroll
            for (int i = 0; i < 4; ++i)
                ob[(q*4 + i)*264 + ph*32 + vnt*16 + r] = (__bf16)o[i];
        }
        __syncthreads();

        // ---- wo projection (A=ob single, split B) + bias + residual ----
        {
            f32x4 acc = zero4;
            #pragma unroll
            for (int ks = 0; ks < 8; ++ks) {
                bf16x8 af = *(const bf16x8*)(oA + ks*32);
                bf16x8 bh = WCHUNK(48 + ks*2);
                bf16x8 bl = WCHUNK(49 + ks*2);
                acc = MFMA(af, bh, acc);
                acc = MFMA(af, bl, acc);
            }
            #pragma unroll
            for (int i = 0; i < 4; ++i) {
                int row = q*4 + i, col = nc + r;
                zf[row*256 + col] = acc[i] + bo[col] + zf[row*256 + col];
            }
        }
        __syncthreads();
        do_ln(g1, b1);
        __syncthreads();

        // ---- FF1: relu(z @ f1^T + fb1) -> ob (split A x split B) ----
        {
            f32x4 acc = zero4;
            #pragma unroll
            for (int ks = 0; ks < 8; ++ks) {
                bf16x8 afh = *(const bf16x8*)(zA_h + ks*32);
                bf16x8 afl = *(const bf16x8*)(zA_l + ks*32);
                bf16x8 bh  = WCHUNK(64 + ks*2);
                bf16x8 bl  = WCHUNK(65 + ks*2);
                acc = MFMA(afh, bh, acc);
                acc = MFMA(afl, bh, acc);
                acc = MFMA(afh, bl, acc);
            }
            #pragma unroll
            for (int i = 0; i < 4; ++i) {
                int row = q*4 + i, col = nc + r;
                ob[row*264 + col] = (__bf16)fmaxf(acc[i] + fb1[col], 0.0f);
            }
        }
        __syncthreads();

        // ---- FF2 (A=ob single, split B) + bias + residual ----
        {
            f32x4 acc = zero4;
            #pragma unroll
            for (int ks = 0; ks < 8; ++ks) {
                bf16x8 af = *(const bf16x8*)(oA + ks*32);
                bf16x8 bh = WCHUNK(80 + ks*2);
                bf16x8 bl = WCHUNK(81 + ks*2);
                acc = MFMA(af, bh, acc);
                acc = MFMA(af, bl, acc);
            }
            #pragma unroll
            for (int i = 0; i < 4; ++i) {
                int row = q*4 + i, col = nc + r;
                zf[row*256 + col] = acc[i] + fb2[col] + zf[row*256 + col];
            }
        }
        __syncthreads();
        do_ln(g2, b2);
        __syncthreads();
        #undef WCHUNK
    }

    // ---- emit final z split as bf16 [A_N][4096] for the CANN GEMM ----
    {
        int row = t >> 6, col = (t & 63) * 4;
        *(bf16x4*)(Zbh + (size_t)a * 4096 + row * 256 + col) =
            *(const bf16x4*)(zbh + row * 264 + col);
        *(bf16x4*)(Zbl + (size_t)a * 4096 + row * 256 + col) =
            *(const bf16x4*)(zbl + row * 264 + col);
    }
}

// ---------------------------------------------------------------------------
// CANN q/k/v GEMM, split-bf16: C[128,4096] = Z @ W^T + b, near-fp32 accuracy.
// BM=128, BN=64, BK=64. grid (64, 3) x 512 (8 waves, 1 block/CU, 192 blocks).
// Pipelined: double-buffered LDS, register staging, 2-deep prefetch, ONE raw
// s_barrier per K-step, NO vmcnt drain (loads for tile t+2 issue at top of
// iter t, consumed at end of iter t+1). The only explicit wait is
// lgkmcnt(0) before the barrier (publish ds_writes); the compiler's precise
// automatic vmcnt(N) covers the register staging.
// A rows padded to 72 bf16. MFMA order per accumulator identical to the
// unpipelined version (bit-identical numerics).
// y==1 (K) is stored TRANSPOSED (KT[4096][128]) for k_cann_scores.
__global__ __launch_bounds__(512) void k_cann_gemm(
    const __bf16* __restrict__ Zh, const __bf16* __restrict__ Zl,
    const float* __restrict__ W0, const float* __restrict__ W1, const float* __restrict__ W2,
    const float* __restrict__ b0, const float* __restrict__ b1, const float* __restrict__ b2,
    float* __restrict__ C0, float* __restrict__ C1, float* __restrict__ C2)
{
    const float* W; const float* bias; float* C;
    if (blockIdx.y == 0)      { W = W0; bias = b0; C = C0; }
    else if (blockIdx.y == 1) { W = W1; bias = b1; C = C1; }
    else                      { W = W2; bias = b2; C = C2; }

    __shared__ __bf16 AshB[2][128 * 72];
    __shared__ __bf16 AslB[2][128 * 72];
    __shared__ __bf16 BshB[2][64 * 72];
    __shared__ __bf16 BslB[2][64 * 72];

    const int t = threadIdx.x;
    const int w = t >> 6, lane = t & 63, q = lane >> 4, r = lane & 15;
    const int n0 = blockIdx.x * 64;
    const int m0 = (w >> 1) * 32;     // wave's M base (4 M-quadrants)
    const int nw = (w & 1) * 32;      // wave's N base within block (2 halves)

    // staging coords: A thread covers rows ar0 and ar0+64, 8 bf16 at col ac
    const int ar0 = t >> 3, ac = (t & 7) * 8;
    const int br  = t >> 3, bc = (t & 7) * 8;   // B: 64 rows x 8 fp32

    struct Stage { bf16x8 a0h, a1h, a0l, a1l; float4 wx, wy; };

    auto issue = [&](Stage& S, int k0) {
        S.a0h = *(const bf16x8*)(Zh + (size_t)ar0        * FLATD + k0 + ac);
        S.a1h = *(const bf16x8*)(Zh + (size_t)(ar0 + 64) * FLATD + k0 + ac);
        S.a0l = *(const bf16x8*)(Zl + (size_t)ar0        * FLATD + k0 + ac);
        S.a1l = *(const bf16x8*)(Zl + (size_t)(ar0 + 64) * FLATD + k0 + ac);
        const float4* wp = (const float4*)(W + (size_t)(n0 + br) * FLATD + k0 + bc);
        S.wx = wp[0]; S.wy = wp[1];
    };

    auto wr = [&](const Stage& S, int b) {
        *(bf16x8*)(&AshB[b][ar0 * 72 + ac])        = S.a0h;
        *(bf16x8*)(&AshB[b][(ar0 + 64) * 72 + ac]) = S.a1h;
        *(bf16x8*)(&AslB[b][ar0 * 72 + ac])        = S.a0l;
        *(bf16x8*)(&AslB[b][(ar0 + 64) * 72 + ac]) = S.a1l;
        float v[8] = {S.wx.x, S.wx.y, S.wx.z, S.wx.w, S.wy.x, S.wy.y, S.wy.z, S.wy.w};
        bf16x8 h, l;
        #pragma unroll
        for (int j = 0; j < 8; ++j) {
            __bf16 hh = (__bf16)v[j];
            h[j] = hh;
            l[j] = (__bf16)(v[j] - (float)hh);
        }
        *(bf16x8*)(&BshB[b][br * 72 + bc]) = h;
        *(bf16x8*)(&BslB[b][br * 72 + bc]) = l;
    };

    const f32x4 zero4 = {0.f, 0.f, 0.f, 0.f};
    f32x4 acc[2][2] = {{zero4, zero4}, {zero4, zero4}};

    auto mfma_phase = [&](int b) {
        #pragma unroll
        for (int ks = 0; ks < 2; ++ks) {
            bf16x8 a0h = *(const bf16x8*)(&AshB[b][(m0 + r)      * 72 + ks*32 + q*8]);
            bf16x8 a1h = *(const bf16x8*)(&AshB[b][(m0 + 16 + r) * 72 + ks*32 + q*8]);
            bf16x8 a0l = *(const bf16x8*)(&AslB[b][(m0 + r)      * 72 + ks*32 + q*8]);
            bf16x8 a1l = *(const bf16x8*)(&AslB[b][(m0 + 16 + r) * 72 + ks*32 + q*8]);
            bf16x8 g0h = *(const bf16x8*)(&BshB[b][(nw + r)      * 72 + ks*32 + q*8]);
            bf16x8 g1h = *(const bf16x8*)(&BshB[b][(nw + 16 + r) * 72 + ks*32 + q*8]);
            bf16x8 g0l = *(const bf16x8*)(&BslB[b][(nw + r)      * 72 + ks*32 + q*8]);
            bf16x8 g1l = *(const bf16x8*)(&BslB[b][(nw + 16 + r) * 72 + ks*32 + q*8]);
            acc[0][0] = MFMA(a0h, g0h, acc[0][0]);
            acc[0][0] = MFMA(a0l, g0h, acc[0][0]);
            acc[0][0] = MFMA(a0h, g0l, acc[0][0]);
            acc[0][1] = MFMA(a0h, g1h, acc[0][1]);
            acc[0][1] = MFMA(a0l, g1h, acc[0][1]);
            acc[0][1] = MFMA(a0h, g1l, acc[0][1]);
            acc[1][0] = MFMA(a1h, g0h, acc[1][0]);
            acc[1][0] = MFMA(a1l, g0h, acc[1][0]);
            acc[1][0] = MFMA(a1h, g0l, acc[1][0]);
            acc[1][1] = MFMA(a1h, g1h, acc[1][1]);
            acc[1][1] = MFMA(a1l, g1h, acc[1][1]);
            acc[1][1] = MFMA(a1h, g1l, acc[1][1]);
        }
    };

    #define LGKM0_BAR() do {                                      \
        asm volatile("s_waitcnt lgkmcnt(0)" ::: "memory");        \
        __builtin_amdgcn_sched_barrier(0);                        \
        __builtin_amdgcn_s_barrier();                             \
        __builtin_amdgcn_sched_barrier(0);                        \
    } while (0)

    Stage S0, S1;
    // prologue: tiles 0,1 in flight; write tile 0 -> buf 0
    issue(S0, 0);
    issue(S1, 64);
    wr(S0, 0);            // compiler inserts vmcnt(6): waits S0 only
    LGKM0_BAR();

    int cur = 0;
    int kk  = 128;        // next tile's k0
    // 31 double-iterations = tiles 0..61
    for (int it = 0; it < 31; ++it) {
        // even step: compute tile 2it from buf[cur]
        issue(S0, kk); kk += 64;            // tile 2it+2
        mfma_phase(cur);
        wr(S1, cur ^ 1);                    // tile 2it+1 (vmcnt(6) auto)
        LGKM0_BAR();
        cur ^= 1;
        // odd step: compute tile 2it+1
        issue(S1, kk); kk += 64;            // tile 2it+3
        mfma_phase(cur);
        wr(S0, cur ^ 1);                    // tile 2it+2
        LGKM0_BAR();
        cur ^= 1;
    }
    // tile 62: no more issues; write tile 63 (S1, vmcnt(0) auto)
    mfma_phase(cur);
    wr(S1, cur ^ 1);
    LGKM0_BAR();
    cur ^= 1;
    // tile 63
    mfma_phase(cur);
    #undef LGKM0_BAR

    if (blockIdx.y == 1) {
        // KT[col][row] = acc + bias[col]
        #pragma unroll
        for (int mi = 0; mi < 2; ++mi)
            #pragma unroll
            for (int ni = 0; ni < 2; ++ni)
                #pragma unroll
                for (int i = 0; i < 4; ++i) {
                    int row = m0 + mi*16 + q*4 + i;
                    int col = n0 + nw + ni*16 + r;
                    C[(size_t)col * 128 + row] = acc[mi][ni][i] + bias[col];
                }
    } else {
        #pragma unroll
        for (int mi = 0; mi < 2; ++mi)
            #pragma unroll
            for (int ni = 0; ni < 2; ++ni)
                #pragma unroll
                for (int i = 0; i < 4; ++i) {
                    int row = m0 + mi*16 + q*4 + i;
                    int col = n0 + nw + ni*16 + r;
                    C[(size_t)row * FLATD + col] = acc[mi][ni][i] + bias[col];
                }
    }
}

// ---------------------------------------------------------------------------
// CANN scores + softmax, 2 Q-rows per block (amortizes the KT stream):
// P[i][j] = softmax_j(Q[i]·K[j] / 16). KT is [4096][128] (k-major).
// 512 threads: j = t&127, 4-way k-split (t>>7). Q rows staged in LDS.
__global__ __launch_bounds__(512) void k_cann_scores(const float* __restrict__ Q,
                              const float* __restrict__ KT,
                              float* __restrict__ P) {
    const int i0 = blockIdx.x * 2;
    const int t  = threadIdx.x;
    __shared__ float qs[2][FLATD];
    __shared__ float part[4][2][128];
    __shared__ float wred[2][2];
    __shared__ float wsum[2][2];
    {
        const float4* src = (const float4*)(Q + (size_t)i0 * FLATD);
        float4* dst = (float4*)qs;
        #pragma unroll
        for (int u = 0; u < 4; ++u) dst[t + u * 512] = src[t + u * 512];
    }
    __syncthreads();

    const int j = t & 127, ksub = t >> 7;
    const float* kp = KT + (size_t)(ksub * 1024) * 128 + j;
    const float* q0 = qs[0] + ksub * 1024;
    const float* q1 = qs[1] + ksub * 1024;
    float a0 = 0.0f, a1 = 0.0f;
    #pragma unroll 8
    for (int k = 0; k < 1024; ++k) {
        float kv = kp[(size_t)k * 128];
        a0 += q0[k] * kv;
        a1 += q1[k] * kv;
    }
    part[ksub][0][j] = a0;
    part[ksub][1][j] = a1;
    __syncthreads();

    // t < 256: i = t>>7, j = t&127; softmax per row across 2 waves
    float v = 0.0f, e = 0.0f;
    const int i = t >> 7;
    if (t < 256)
        v = (part[0][i][j] + part[1][i][j] + part[2][i][j] + part[3][i][j]) * 0.0625f;

    float mx = (t < 256) ? v : -3.4e38f;
    #pragma unroll
    for (int o = 32; o; o >>= 1) mx = fmaxf(mx, __shfl_xor(mx, o));
    if (t < 256 && (j & 63) == 0) wred[i][j >> 6] = mx;
    __syncthreads();
    if (t < 256) {
        mx = fmaxf(wred[i][0], wred[i][1]);
        e = __expf(v - mx);
    }
    float sum = e;
    #pragma unroll
    for (int o = 32; o; o >>= 1) sum += __shfl_xor(sum, o);
    if (t < 256 && (j & 63) == 0) wsum[i][j >> 6] = sum;
    __syncthreads();
    if (t < 256) {
        sum = wsum[i][0] + wsum[i][1];
        P[(size_t)(i0 + i) * 128 + j] = e / sum;
    }
}

// ---------------------------------------------------------------------------
// H[i][n] = sum_j P[i][j] * V[j][n]. 8 rows x 1024-col tile per block:
// V traffic 268 MB -> 32 MB. P staged transposed (ps[j][i]) for b128 reads.
__global__ __launch_bounds__(256) void k_cann_out(const float* __restrict__ P,
                           const float* __restrict__ V,
                           float* __restrict__ H) {
    const int i0 = blockIdx.y * 8;
    const int t  = threadIdx.x;
    const int nb = blockIdx.x * 1024 + t * 4;
    __shared__ float ps[128][8];
    #pragma unroll
    for (int u = 0; u < 4; ++u) {
        int e = t + u * 256;            // 0..1023
        int i = e >> 7, j = e & 127;
        ps[j][i] = P[(size_t)(i0 + i) * 128 + j];
    }
    __syncthreads();

    f32x4 acc[8];
    #pragma unroll
    for (int i = 0; i < 8; ++i) acc[i] = (f32x4){0.f, 0.f, 0.f, 0.f};

    for (int j = 0; j < 128; ++j) {
        float4 vv = *(const float4*)(V + (size_t)j * FLATD + nb);
        f32x4 v4 = {vv.x, vv.y, vv.z, vv.w};
        float4 pa = *(const float4*)&ps[j][0];
        float4 pb = *(const float4*)&ps[j][4];
        acc[0] += pa.x * v4; acc[1] += pa.y * v4;
        acc[2] += pa.z * v4; acc[3] += pa.w * v4;
        acc[4] += pb.x * v4; acc[5] += pb.y * v4;
        acc[6] += pb.z * v4; acc[7] += pb.w * v4;
    }
    #pragma unroll
    for (int i = 0; i < 8; ++i) {
        f32x4 a = acc[i];
        *(float4*)(H + (size_t)(i0 + i) * FLATD + nb) =
            (float4){a[0], a[1], a[2], a[3]};
    }
}

// ---------------------------------------------------------------------------
extern "C" void kernel_launch(void* const* d_in, const int* in_sizes, int n_in,
                              void* d_out, int out_size, void* d_ws, size_t ws_size,
                              hipStream_t stream) {
    (void)in_sizes; (void)n_in; (void)out_size; (void)ws_size;

    const float* z      = (const float*)d_in[1];
    const float* s_wq   = (const float*)d_in[15];
    const float* s_wk   = (const float*)d_in[16];
    const float* s_wv   = (const float*)d_in[17];
    const float* s_wo   = (const float*)d_in[18];
    const float* s_bo   = (const float*)d_in[19];
    const float* s_ln1g = (const float*)d_in[20];
    const float* s_ln1b = (const float*)d_in[21];
    const float* s_fw1  = (const float*)d_in[22];
    const float* s_fb1  = (const float*)d_in[23];
    const float* s_fw2  = (const float*)d_in[24];
    const float* s_fb2  = (const float*)d_in[25];
    const float* s_ln2g = (const float*)d_in[26];
    const float* s_ln2b = (const float*)d_in[27];
    const float* q_w    = (const float*)d_in[28];
    const float* q_b    = (const float*)d_in[29];
    const float* k_w    = (const float*)d_in[30];
    const float* k_b    = (const float*)d_in[31];
    const float* v_w    = (const float*)d_in[32];
    const float* v_b    = (const float*)d_in[33];

    float* out    = (float*)d_out;
    float* Hout   = out;
    float* Zprior = out + 524288;

    // Workspace: [0,6MB) = Wswz, later reused as Qb/KT/Vb (Wswz dead by then)
    char* w8 = (char*)d_ws;
    __bf16* Wswz = (__bf16*)w8;                    // 6.29 MB swizzled weights
    float*  Qb  = (float*)w8;                      // 2 MB (aliases Wswz)
    float*  Kb  = (float*)(w8 + 2097152);          // 2 MB (KT[4096][128])
    float*  Vb  = (float*)(w8 + 4194304);          // 2 MB
    __bf16* Zbh = (__bf16*)(w8 + 6291456);         // 1 MB
    __bf16* Zbl = (__bf16*)(w8 + 7340032);         // 1 MB
    float*  Pm  = (float*)(w8 + 8388608);          // 64 KB

    k_cvt_w<<<1536, 256, 0, stream>>>(s_wq, s_wk, s_wv, s_wo, s_fw1, s_fw2, Wswz);

    k_latent<<<A_N, 1024, 0, stream>>>(z, Wswz, s_bo, s_ln1g, s_ln1b,
                                       s_fb1, s_fb2, s_ln2g, s_ln2b,
                                       Zprior, Zbh, Zbl);

    k_cann_gemm<<<dim3(FLATD / 64, 3), 512, 0, stream>>>(Zbh, Zbl, q_w, k_w, v_w,
                                                         q_b, k_b, v_b, Qb, Kb, Vb);

    k_cann_scores<<<A_N / 2, 512, 0, stream>>>(Qb, Kb, Pm);
    k_cann_out<<<dim3(4, 16), 256, 0, stream>>>(Pm, Vb, Hout);
}

// Round 5
// 514.223 us; speedup vs baseline: 1.2852x; 1.0110x over previous
//
#include <hip/hip_runtime.h>
#include <math.h>

typedef __bf16 bf16x8 __attribute__((ext_vector_type(8)));
typedef __bf16 bf16x4 __attribute__((ext_vector_type(4)));
typedef float  f32x4  __attribute__((ext_vector_type(4)));

#define MFMA(a,b,c) __builtin_amdgcn_mfma_f32_16x16x32_bf16((a),(b),(c),0,0,0)

#define A_N   128
#define LDIM  256
#define FLATD 4096

// ---------------------------------------------------------------------------
// Repack the 6 latent weight arrays (each [4][256][256] fp32) into split bf16
// (hi + lo) laid out in per-wave consumption order for k_latent (see decode
// below). v2: COALESCED READS (each thread reads 8 contiguous floats; a wave
// covers 2 KB sequential), scattered writes (stores are fire-and-forget).
// Stream layout (bf16 index): (lp*16+w)*49152 + li*512 + lane*8, where
//   li (96 chunks/stream): m<3: ks*6+m*2+hl ; m=3: 48+ks*2+hl ;
//                          m=4: 64+ks*2+hl ; m=5: 80+ks*2+hl
//   chunk(lp,w,li,lane) = W[m][lp][w*16+(lane&15)][ks*32+(lane>>4)*8 + j]
__global__ __launch_bounds__(256) void k_cvt_w(
        const float* __restrict__ s0, const float* __restrict__ s1,
        const float* __restrict__ s2, const float* __restrict__ s3,
        const float* __restrict__ s4, const float* __restrict__ s5,
        __bf16* __restrict__ W) {
    const int gid = blockIdx.x * 256 + threadIdx.x;    // 0..196607
    const int m   = gid >> 15;                         // matrix 0..5
    const int rem = gid & 32767;
    const int off = rem << 3;                          // float offset in matrix
    const int lp  = off >> 16;
    const int win = off & 65535;
    const int row = win >> 8;                          // 0..255
    const int c   = win & 255;                         // col, multiple of 8
    const int w   = row >> 4, lr = row & 15;
    const int ks  = c >> 5,  q  = (c >> 3) & 3;
    const int lane = q * 16 + lr;

    int li_h;
    if (m < 3)       li_h = ks * 6 + m * 2;
    else if (m == 3) li_h = 48 + ks * 2;
    else if (m == 4) li_h = 64 + ks * 2;
    else             li_h = 80 + ks * 2;

    const float* s;
    switch (m) {
        case 0: s = s0; break; case 1: s = s1; break; case 2: s = s2; break;
        case 3: s = s3; break; case 4: s = s4; break; default: s = s5; break;
    }
    const float4* sp = (const float4*)(s + off);
    float4 x = sp[0], y = sp[1];
    float v[8] = {x.x, x.y, x.z, x.w, y.x, y.y, y.z, y.w};
    bf16x8 h, l;
    #pragma unroll
    for (int j = 0; j < 8; ++j) {
        __bf16 hh = (__bf16)v[j];
        h[j] = hh;
        l[j] = (__bf16)(v[j] - (float)hh);
    }
    __bf16* dst = W + (size_t)(lp * 16 + w) * 49152 + (size_t)lane * 8;
    *(bf16x8*)(dst + (size_t)li_h * 512)       = h;
    *(bf16x8*)(dst + (size_t)(li_h + 1) * 512) = l;
}

// ---------------------------------------------------------------------------
// Fused 4-layer latent transformer, split-bf16 (near-fp32) projections.
// One block per asset (16 rows x 256). 1024 threads = 16 waves.
// Weights pre-swizzled (k_cvt_w): wave w reads ONE contiguous 96 KB stream
// per layer, 1 KB per wave-load -- fully coalesced, sequential addresses.
// MFMA 16x16x32 bf16 layouts (verified m89/m91):
//   A[m=lane&15][k=(lane>>4)*8+j], B[n=lane&15][k=(lane>>4)*8+j]
//   C[m=(lane>>4)*4+reg][n=lane&15]
__global__ __launch_bounds__(1024) void k_latent(
    const float* __restrict__ z,
    const __bf16* __restrict__ Wswz,
    const float* __restrict__ boa,
    const float* __restrict__ g1a, const float* __restrict__ b1a,
    const float* __restrict__ fb1a, const float* __restrict__ fb2a,
    const float* __restrict__ g2a, const float* __restrict__ b2a,
    float* __restrict__ zprior, __bf16* __restrict__ Zbh, __bf16* __restrict__ Zbl)
{
    // LDS arena 57856 B. Aliases (barrier-guarded):
    //   Ph  aliases zbh (zb dead between qkv-proj and LN1)
    //   ob  aliases Qh + first 256 B of Kh (dead after scores)
    __shared__ __align__(16) char arena[57856];
    float*  zf  = (float*)arena;                    // [16][256] f32 residual
    __bf16* zbh = (__bf16*)(arena + 16384);         // [16][264]
    __bf16* zbl = (__bf16*)(arena + 24832);         // [16][264]
    __bf16* Ph  = (__bf16*)(arena + 16384);         // [8][16][32] (k-pad 0)
    __bf16* Qh  = (__bf16*)(arena + 33280);         // [8][16][32]
    __bf16* ob  = Qh;                               // [16][264]
    __bf16* Kh  = (__bf16*)(arena + 41472);         // [8][16][32]
    __bf16* Vt  = (__bf16*)(arena + 49664);         // [8][32][16] V^T compact

    const int a    = blockIdx.x;
    const int t    = threadIdx.x;
    const int w    = t >> 6;          // 0..15
    const int lane = t & 63;
    const int q    = lane >> 4;
    const int r    = lane & 15;
    const int nc   = w * 16;          // GEMM output col base for this wave
    const int head = w >> 1;          // attention head for qkv store
    const int hc   = (w & 1) * 16;    // col-half within head

    // ---- load z -> zf, zbh/zbl; emit z_prior (4 floats/thread) ----
    {
        int row = t >> 6, col = (t & 63) * 4;
        const float4 x = *(const float4*)(z + (size_t)a * 4096 + row * 256 + col);
        *(float4*)(zprior + (size_t)a * 4096 + row * 256 + col) = x;
        float v[4] = {x.x, x.y, x.z, x.w};
        float*  zr = zf  + row * 256 + col;
        __bf16* zh = zbh + row * 264 + col;
        __bf16* zl = zbl + row * 264 + col;
        #pragma unroll
        for (int j = 0; j < 4; ++j) {
            zr[j] = v[j];
            __bf16 hh = (__bf16)v[j];
            zh[j] = hh;
            zl[j] = (__bf16)(v[j] - (float)hh);
        }
    }
    __syncthreads();

    // wave w handles row w (64 lanes x 4 cols)
    auto do_ln = [&](const float* g, const float* bb) {
        int col = lane * 4;
        float* zr = zf + w * 256 + col;
        float4 v4 = *(const float4*)zr;
        float v[4] = {v4.x, v4.y, v4.z, v4.w};
        float s1 = 0.f, s2 = 0.f;
        #pragma unroll
        for (int j = 0; j < 4; ++j) { s1 += v[j]; s2 += v[j]*v[j]; }
        #pragma unroll
        for (int o = 1; o <= 32; o <<= 1) {
            s1 += __shfl_xor(s1, o);
            s2 += __shfl_xor(s2, o);
        }
        float mean = s1 * (1.0f/256.0f);
        float var  = s2 * (1.0f/256.0f) - mean * mean;
        float inv  = rsqrtf(var + 1e-5f);
        float4 g4 = *(const float4*)(g + col);
        float4 b4 = *(const float4*)(bb + col);
        float gg[4] = {g4.x, g4.y, g4.z, g4.w};
        float bbv[4] = {b4.x, b4.y, b4.z, b4.w};
        __bf16* zh = zbh + w * 264 + col;
        __bf16* zl = zbl + w * 264 + col;
        float y[4];
        #pragma unroll
        for (int j = 0; j < 4; ++j) {
            y[j] = (v[j] - mean) * inv * gg[j] + bbv[j];
            __bf16 hh = (__bf16)y[j];
            zh[j] = hh;
            zl[j] = (__bf16)(y[j] - (float)hh);
        }
        *(float4*)zr = (float4){y[0], y[1], y[2], y[3]};
    };

    const f32x4 zero4 = {0.f, 0.f, 0.f, 0.f};
    bf16x8 zer8;
    #pragma unroll
    for (int j = 0; j < 8; ++j) zer8[j] = (__bf16)0.0f;

    for (int lp = 0; lp < 4; ++lp) {
        const float* bo  = boa  + lp*256;
        const float* g1  = g1a  + lp*256; const float* b1 = b1a + lp*256;
        const float* fb1 = fb1a + lp*256; const float* fb2 = fb2a + lp*256;
        const float* g2  = g2a  + lp*256; const float* b2 = b2a + lp*256;

        // per-wave contiguous weight stream (see k_cvt_w layout comment)
        const __bf16* wsl = Wswz + (size_t)(lp * 16 + w) * 49152 + (size_t)lane * 8;
        #define WCHUNK(idx) (*(const bf16x8*)(wsl + (idx) * 512))

        const __bf16* zA_h = zbh + r * 264 + q * 8;          // A frag base
        const __bf16* zA_l = zbl + r * 264 + q * 8;
        const __bf16* oA   = ob  + r * 264 + q * 8;

        // ---- q,k,v projections: 3 interleaved split-product chains ----
        {
            f32x4 aq = zero4, ak = zero4, av = zero4;
            #pragma unroll
            for (int ks = 0; ks < 8; ++ks) {
                bf16x8 afh = *(const bf16x8*)(zA_h + ks*32);
                bf16x8 afl = *(const bf16x8*)(zA_l + ks*32);
                bf16x8 qh = WCHUNK(ks*6 + 0);
                bf16x8 ql = WCHUNK(ks*6 + 1);
                bf16x8 kh = WCHUNK(ks*6 + 2);
                bf16x8 kl = WCHUNK(ks*6 + 3);
                bf16x8 vh = WCHUNK(ks*6 + 4);
                bf16x8 vl = WCHUNK(ks*6 + 5);
                aq = MFMA(afh, qh, aq); aq = MFMA(afl, qh, aq); aq = MFMA(afh, ql, aq);
                ak = MFMA(afh, kh, ak); ak = MFMA(afl, kh, ak); ak = MFMA(afh, kl, ak);
                av = MFMA(afh, vh, av); av = MFMA(afl, vh, av); av = MFMA(afh, vl, av);
            }
            #pragma unroll
            for (int i = 0; i < 4; ++i) {
                int m = q*4 + i;
                Qh[(head*16 + m)*32 + hc + r] = (__bf16)aq[i];
                Kh[(head*16 + m)*32 + hc + r] = (__bf16)ak[i];
                Vt[(head*32 + hc + r)*16 + m] = (__bf16)av[i];
            }
        }
        __syncthreads();   // Qh/Kh/Vt visible; zb reads done (Ph may alias)

        // ---- scores + softmax, head w per wave (waves 0..7 only) ----
        if (w < 8) {
            bf16x8 qa = *(const bf16x8*)(Qh + (w*16 + r)*32 + q*8);
            bf16x8 ka = *(const bf16x8*)(Kh + (w*16 + r)*32 + q*8);
            f32x4 s = MFMA(qa, ka, zero4);   // S[i=q*4+reg][j=r], K = hd = 32
            #pragma unroll
            for (int i = 0; i < 4; ++i) {
                float sc = s[i] * 0.17677669529663687f;
                float mx = sc;
                #pragma unroll
                for (int o = 1; o <= 8; o <<= 1) mx = fmaxf(mx, __shfl_xor(mx, o, 16));
                float e = __expf(sc - mx);
                float sm = e;
                #pragma unroll
                for (int o = 1; o <= 8; o <<= 1) sm += __shfl_xor(sm, o, 16);
                Ph[(w*16 + q*4 + i)*32 + r]      = (__bf16)(e / sm);
                Ph[(w*16 + q*4 + i)*32 + 16 + r] = (__bf16)0.0f;   // k-pad
            }
        }
        __syncthreads();   // all Qh/Kh reads done (ob may alias)

        // ---- O = P @ V. 16 waves: head = w&7, d-half = w>>3 ----
        {
            int ph = w & 7, vnt = w >> 3;
            bf16x8 pa = *(const bf16x8*)(Ph + (ph*16 + r)*32 + q*8);
            bf16x8 vb = (q < 2)
                ? *(const bf16x8*)(Vt + (ph*32 + vnt*16 + r)*16 + q*8) : zer8;
            f32x4 o = MFMA(pa, vb, zero4);   // O[i=q*4+reg][d=vnt*16+r]
            #pragma unroll
            for (int i = 0; i < 4; ++i)
                ob[(q*4 + i)*264 + ph*32 + vnt*16 + r] = (__bf16)o[i];
        }
        __syncthreads();

        // ---- wo projection (A=ob single, split B) + bias + residual ----
        {
            f32x4 acc = zero4;
            #pragma unroll
            for (int ks = 0; ks < 8; ++ks) {
                bf16x8 af = *(const bf16x8*)(oA + ks*32);
                bf16x8 bh = WCHUNK(48 + ks*2);
                bf16x8 bl = WCHUNK(49 + ks*2);
                acc = MFMA(af, bh, acc);
                acc = MFMA(af, bl, acc);
            }
            #pragma unroll
            for (int i = 0; i < 4; ++i) {
                int row = q*4 + i, col = nc + r;
                zf[row*256 + col] = acc[i] + bo[col] + zf[row*256 + col];
            }
        }
        __syncthreads();
        do_ln(g1, b1);
        __syncthreads();

        // ---- FF1: relu(z @ f1^T + fb1) -> ob (split A x split B) ----
        {
            f32x4 acc = zero4;
            #pragma unroll
            for (int ks = 0; ks < 8; ++ks) {
                bf16x8 afh = *(const bf16x8*)(zA_h + ks*32);
                bf16x8 afl = *(const bf16x8*)(zA_l + ks*32);
                bf16x8 bh  = WCHUNK(64 + ks*2);
                bf16x8 bl  = WCHUNK(65 + ks*2);
                acc = MFMA(afh, bh, acc);
                acc = MFMA(afl, bh, acc);
                acc = MFMA(afh, bl, acc);
            }
            #pragma unroll
            for (int i = 0; i < 4; ++i) {
                int row = q*4 + i, col = nc + r;
                ob[row*264 + col] = (__bf16)fmaxf(acc[i] + fb1[col], 0.0f);
            }
        }
        __syncthreads();

        // ---- FF2 (A=ob single, split B) + bias + residual ----
        {
            f32x4 acc = zero4;
            #pragma unroll
            for (int ks = 0; ks < 8; ++ks) {
                bf16x8 af = *(const bf16x8*)(oA + ks*32);
                bf16x8 bh = WCHUNK(80 + ks*2);
                bf16x8 bl = WCHUNK(81 + ks*2);
                acc = MFMA(af, bh, acc);
                acc = MFMA(af, bl, acc);
            }
            #pragma unroll
            for (int i = 0; i < 4; ++i) {
                int row = q*4 + i, col = nc + r;
                zf[row*256 + col] = acc[i] + fb2[col] + zf[row*256 + col];
            }
        }
        __syncthreads();
        do_ln(g2, b2);
        __syncthreads();
        #undef WCHUNK
    }

    // ---- emit final z split as bf16 [A_N][4096] for the CANN GEMM ----
    {
        int row = t >> 6, col = (t & 63) * 4;
        *(bf16x4*)(Zbh + (size_t)a * 4096 + row * 256 + col) =
            *(const bf16x4*)(zbh + row * 264 + col);
        *(bf16x4*)(Zbl + (size_t)a * 4096 + row * 256 + col) =
            *(const bf16x4*)(zbl + row * 264 + col);
    }
}

// ---------------------------------------------------------------------------
// CANN q/k/v GEMM, split-bf16: C[128,4096] = Z @ W^T + b, near-fp32 accuracy.
// BM=128, BN=64, BK=64. grid (64, 3) x 512 (8 waves, 1 block/CU, 192 blocks).
// Pipelined: double-buffered LDS, register staging, 2-deep prefetch, ONE raw
// s_barrier per K-step, NO vmcnt drain. v3: ALL staging loads are
// NONTEMPORAL (bypass L1). Rationale: A rows are 8 KB apart, W rows 16 KB
// apart -- both are multiples of the 32 KB L1's set period, so every
// wave-load put 8 lines into ONE 4-way set and issue() put 32 same-set
// lines in flight -> L1 MSHR thrash serialized the stream at ~13 B/cyc/CU.
// A's reuse lives in LDS and W has none, so L1 adds nothing here.
// A rows padded to 72 bf16. MFMA order per accumulator unchanged
// (bit-identical numerics). y==1 (K) stored transposed (KT[4096][128]).
__global__ __launch_bounds__(512) void k_cann_gemm(
    const __bf16* __restrict__ Zh, const __bf16* __restrict__ Zl,
    const float* __restrict__ W0, const float* __restrict__ W1, const float* __restrict__ W2,
    const float* __restrict__ b0, const float* __restrict__ b1, const float* __restrict__ b2,
    float* __restrict__ C0, float* __restrict__ C1, float* __restrict__ C2)
{
    const float* W; const float* bias; float* C;
    if (blockIdx.y == 0)      { W = W0; bias = b0; C = C0; }
    else if (blockIdx.y == 1) { W = W1; bias = b1; C = C1; }
    else                      { W = W2; bias = b2; C = C2; }

    __shared__ __bf16 AshB[2][128 * 72];
    __shared__ __bf16 AslB[2][128 * 72];
    __shared__ __bf16 BshB[2][64 * 72];
    __shared__ __bf16 BslB[2][64 * 72];

    const int t = threadIdx.x;
    const int w = t >> 6, lane = t & 63, q = lane >> 4, r = lane & 15;
    const int n0 = blockIdx.x * 64;
    const int m0 = (w >> 1) * 32;     // wave's M base (4 M-quadrants)
    const int nw = (w & 1) * 32;      // wave's N base within block (2 halves)

    // staging coords: A thread covers rows ar0 and ar0+64, 8 bf16 at col ac
    const int ar0 = t >> 3, ac = (t & 7) * 8;
    const int br  = t >> 3, bc = (t & 7) * 8;   // B: 64 rows x 8 fp32

    struct Stage { bf16x8 a0h, a1h, a0l, a1l; f32x4 wx, wy; };

    auto issue = [&](Stage& S, int k0) {
        S.a0h = __builtin_nontemporal_load(
                    (const bf16x8*)(Zh + (size_t)ar0        * FLATD + k0 + ac));
        S.a1h = __builtin_nontemporal_load(
                    (const bf16x8*)(Zh + (size_t)(ar0 + 64) * FLATD + k0 + ac));
        S.a0l = __builtin_nontemporal_load(
                    (const bf16x8*)(Zl + (size_t)ar0        * FLATD + k0 + ac));
        S.a1l = __builtin_nontemporal_load(
                    (const bf16x8*)(Zl + (size_t)(ar0 + 64) * FLATD + k0 + ac));
        const f32x4* wp = (const f32x4*)(W + (size_t)(n0 + br) * FLATD + k0 + bc);
        S.wx = __builtin_nontemporal_load(wp);
        S.wy = __builtin_nontemporal_load(wp + 1);
    };

    auto wr = [&](const Stage& S, int b) {
        *(bf16x8*)(&AshB[b][ar0 * 72 + ac])        = S.a0h;
        *(bf16x8*)(&AshB[b][(ar0 + 64) * 72 + ac]) = S.a1h;
        *(bf16x8*)(&AslB[b][ar0 * 72 + ac])        = S.a0l;
        *(bf16x8*)(&AslB[b][(ar0 + 64) * 72 + ac]) = S.a1l;
        float v[8] = {S.wx[0], S.wx[1], S.wx[2], S.wx[3],
                      S.wy[0], S.wy[1], S.wy[2], S.wy[3]};
        bf16x8 h, l;
        #pragma unroll
        for (int j = 0; j < 8; ++j) {
            __bf16 hh = (__bf16)v[j];
            h[j] = hh;
            l[j] = (__bf16)(v[j] - (float)hh);
        }
        *(bf16x8*)(&BshB[b][br * 72 + bc]) = h;
        *(bf16x8*)(&BslB[b][br * 72 + bc]) = l;
    };

    const f32x4 zero4 = {0.f, 0.f, 0.f, 0.f};
    f32x4 acc[2][2] = {{zero4, zero4}, {zero4, zero4}};

    auto mfma_phase = [&](int b) {
        #pragma unroll
        for (int ks = 0; ks < 2; ++ks) {
            bf16x8 a0h = *(const bf16x8*)(&AshB[b][(m0 + r)      * 72 + ks*32 + q*8]);
            bf16x8 a1h = *(const bf16x8*)(&AshB[b][(m0 + 16 + r) * 72 + ks*32 + q*8]);
            bf16x8 a0l = *(const bf16x8*)(&AslB[b][(m0 + r)      * 72 + ks*32 + q*8]);
            bf16x8 a1l = *(const bf16x8*)(&AslB[b][(m0 + 16 + r) * 72 + ks*32 + q*8]);
            bf16x8 g0h = *(const bf16x8*)(&BshB[b][(nw + r)      * 72 + ks*32 + q*8]);
            bf16x8 g1h = *(const bf16x8*)(&BshB[b][(nw + 16 + r) * 72 + ks*32 + q*8]);
            bf16x8 g0l = *(const bf16x8*)(&BslB[b][(nw + r)      * 72 + ks*32 + q*8]);
            bf16x8 g1l = *(const bf16x8*)(&BslB[b][(nw + 16 + r) * 72 + ks*32 + q*8]);
            acc[0][0] = MFMA(a0h, g0h, acc[0][0]);
            acc[0][0] = MFMA(a0l, g0h, acc[0][0]);
            acc[0][0] = MFMA(a0h, g0l, acc[0][0]);
            acc[0][1] = MFMA(a0h, g1h, acc[0][1]);
            acc[0][1] = MFMA(a0l, g1h, acc[0][1]);
            acc[0][1] = MFMA(a0h, g1l, acc[0][1]);
            acc[1][0] = MFMA(a1h, g0h, acc[1][0]);
            acc[1][0] = MFMA(a1l, g0h, acc[1][0]);
            acc[1][0] = MFMA(a1h, g0l, acc[1][0]);
            acc[1][1] = MFMA(a1h, g1h, acc[1][1]);
            acc[1][1] = MFMA(a1l, g1h, acc[1][1]);
            acc[1][1] = MFMA(a1h, g1l, acc[1][1]);
        }
    };

    #define LGKM0_BAR() do {                                      \
        asm volatile("s_waitcnt lgkmcnt(0)" ::: "memory");        \
        __builtin_amdgcn_sched_barrier(0);                        \
        __builtin_amdgcn_s_barrier();                             \
        __builtin_amdgcn_sched_barrier(0);                        \
    } while (0)

    Stage S0, S1;
    // prologue: tiles 0,1 in flight; write tile 0 -> buf 0
    issue(S0, 0);
    issue(S1, 64);
    wr(S0, 0);            // compiler inserts vmcnt(6): waits S0 only
    LGKM0_BAR();

    int cur = 0;
    int kk  = 128;        // next tile's k0
    // 31 double-iterations = tiles 0..61
    for (int it = 0; it < 31; ++it) {
        // even step: compute tile 2it from buf[cur]
        issue(S0, kk); kk += 64;            // tile 2it+2
        mfma_phase(cur);
        wr(S1, cur ^ 1);                    // tile 2it+1 (vmcnt(6) auto)
        LGKM0_BAR();
        cur ^= 1;
        // odd step: compute tile 2it+1
        issue(S1, kk); kk += 64;            // tile 2it+3
        mfma_phase(cur);
        wr(S0, cur ^ 1);                    // tile 2it+2
        LGKM0_BAR();
        cur ^= 1;
    }
    // tile 62: no more issues; write tile 63 (S1, vmcnt(0) auto)
    mfma_phase(cur);
    wr(S1, cur ^ 1);
    LGKM0_BAR();
    cur ^= 1;
    // tile 63
    mfma_phase(cur);
    #undef LGKM0_BAR

    if (blockIdx.y == 1) {
        // KT[col][row] = acc + bias[col]
        #pragma unroll
        for (int mi = 0; mi < 2; ++mi)
            #pragma unroll
            for (int ni = 0; ni < 2; ++ni)
                #pragma unroll
                for (int i = 0; i < 4; ++i) {
                    int row = m0 + mi*16 + q*4 + i;
                    int col = n0 + nw + ni*16 + r;
                    C[(size_t)col * 128 + row] = acc[mi][ni][i] + bias[col];
                }
    } else {
        #pragma unroll
        for (int mi = 0; mi < 2; ++mi)
            #pragma unroll
            for (int ni = 0; ni < 2; ++ni)
                #pragma unroll
                for (int i = 0; i < 4; ++i) {
                    int row = m0 + mi*16 + q*4 + i;
                    int col = n0 + nw + ni*16 + r;
                    C[(size_t)row * FLATD + col] = acc[mi][ni][i] + bias[col];
                }
    }
}

// ---------------------------------------------------------------------------
// CANN scores + softmax, 2 Q-rows per block (amortizes the KT stream):
// P[i][j] = softmax_j(Q[i]·K[j] / 16). KT is [4096][128] (k-major).
// 512 threads: j = t&127, 4-way k-split (t>>7). Q rows staged in LDS.
__global__ __launch_bounds__(512) void k_cann_scores(const float* __restrict__ Q,
                              const float* __restrict__ KT,
                              float* __restrict__ P) {
    const int i0 = blockIdx.x * 2;
    const int t  = threadIdx.x;
    __shared__ float qs[2][FLATD];
    __shared__ float part[4][2][128];
    __shared__ float wred[2][2];
    __shared__ float wsum[2][2];
    {
        const float4* src = (const float4*)(Q + (size_t)i0 * FLATD);
        float4* dst = (float4*)qs;
        #pragma unroll
        for (int u = 0; u < 4; ++u) dst[t + u * 512] = src[t + u * 512];
    }
    __syncthreads();

    const int j = t & 127, ksub = t >> 7;
    const float* kp = KT + (size_t)(ksub * 1024) * 128 + j;
    const float* q0 = qs[0] + ksub * 1024;
    const float* q1 = qs[1] + ksub * 1024;
    float a0 = 0.0f, a1 = 0.0f;
    #pragma unroll 8
    for (int k = 0; k < 1024; ++k) {
        float kv = kp[(size_t)k * 128];
        a0 += q0[k] * kv;
        a1 += q1[k] * kv;
    }
    part[ksub][0][j] = a0;
    part[ksub][1][j] = a1;
    __syncthreads();

    // t < 256: i = t>>7, j = t&127; softmax per row across 2 waves
    float v = 0.0f, e = 0.0f;
    const int i = t >> 7;
    if (t < 256)
        v = (part[0][i][j] + part[1][i][j] + part[2][i][j] + part[3][i][j]) * 0.0625f;

    float mx = (t < 256) ? v : -3.4e38f;
    #pragma unroll
    for (int o = 32; o; o >>= 1) mx = fmaxf(mx, __shfl_xor(mx, o));
    if (t < 256 && (j & 63) == 0) wred[i][j >> 6] = mx;
    __syncthreads();
    if (t < 256) {
        mx = fmaxf(wred[i][0], wred[i][1]);
        e = __expf(v - mx);
    }
    float sum = e;
    #pragma unroll
    for (int o = 32; o; o >>= 1) sum += __shfl_xor(sum, o);
    if (t < 256 && (j & 63) == 0) wsum[i][j >> 6] = sum;
    __syncthreads();
    if (t < 256) {
        sum = wsum[i][0] + wsum[i][1];
        P[(size_t)(i0 + i) * 128 + j] = e / sum;
    }
}

// ---------------------------------------------------------------------------
// H[i][n] = sum_j P[i][j] * V[j][n]. 8 rows x 1024-col tile per block:
// V traffic 268 MB -> 32 MB. P staged transposed (ps[j][i]) for b128 reads.
__global__ __launch_bounds__(256) void k_cann_out(const float* __restrict__ P,
                           const float* __restrict__ V,
                           float* __restrict__ H) {
    const int i0 = blockIdx.y * 8;
    const int t  = threadIdx.x;
    const int nb = blockIdx.x * 1024 + t * 4;
    __shared__ float ps[128][8];
    #pragma unroll
    for (int u = 0; u < 4; ++u) {
        int e = t + u * 256;            // 0..1023
        int i = e >> 7, j = e & 127;
        ps[j][i] = P[(size_t)(i0 + i) * 128 + j];
    }
    __syncthreads();

    f32x4 acc[8];
    #pragma unroll
    for (int i = 0; i < 8; ++i) acc[i] = (f32x4){0.f, 0.f, 0.f, 0.f};

    for (int j = 0; j < 128; ++j) {
        float4 vv = *(const float4*)(V + (size_t)j * FLATD + nb);
        f32x4 v4 = {vv.x, vv.y, vv.z, vv.w};
        float4 pa = *(const float4*)&ps[j][0];
        float4 pb = *(const float4*)&ps[j][4];
        acc[0] += pa.x * v4; acc[1] += pa.y * v4;
        acc[2] += pa.z * v4; acc[3] += pa.w * v4;
        acc[4] += pb.x * v4; acc[5] += pb.y * v4;
        acc[6] += pb.z * v4; acc[7] += pb.w * v4;
    }
    #pragma unroll
    for (int i = 0; i < 8; ++i) {
        f32x4 a = acc[i];
        *(float4*)(H + (size_t)(i0 + i) * FLATD + nb) =
            (float4){a[0], a[1], a[2], a[3]};
    }
}

// ---------------------------------------------------------------------------
extern "C" void kernel_launch(void* const* d_in, const int* in_sizes, int n_in,
                              void* d_out, int out_size, void* d_ws, size_t ws_size,
                              hipStream_t stream) {
    (void)in_sizes; (void)n_in; (void)out_size; (void)ws_size;

    const float* z      = (const float*)d_in[1];
    const float* s_wq   = (const float*)d_in[15];
    const float* s_wk   = (const float*)d_in[16];
    const float* s_wv   = (const float*)d_in[17];
    const float* s_wo   = (const float*)d_in[18];
    const float* s_bo   = (const float*)d_in[19];
    const float* s_ln1g = (const float*)d_in[20];
    const float* s_ln1b = (const float*)d_in[21];
    const float* s_fw1  = (const float*)d_in[22];
    const float* s_fb1  = (const float*)d_in[23];
    const float* s_fw2  = (const float*)d_in[24];
    const float* s_fb2  = (const float*)d_in[25];
    const float* s_ln2g = (const float*)d_in[26];
    const float* s_ln2b = (const float*)d_in[27];
    const float* q_w    = (const float*)d_in[28];
    const float* q_b    = (const float*)d_in[29];
    const float* k_w    = (const float*)d_in[30];
    const float* k_b    = (const float*)d_in[31];
    const float* v_w    = (const float*)d_in[32];
    const float* v_b    = (const float*)d_in[33];

    float* out    = (float*)d_out;
    float* Hout   = out;
    float* Zprior = out + 524288;

    // Workspace: [0,6MB) = Wswz, later reused as Qb/KT/Vb (Wswz dead by then)
    char* w8 = (char*)d_ws;
    __bf16* Wswz = (__bf16*)w8;                    // 6.29 MB swizzled weights
    float*  Qb  = (float*)w8;                      // 2 MB (aliases Wswz)
    float*  Kb  = (float*)(w8 + 2097152);          // 2 MB (KT[4096][128])
    float*  Vb  = (float*)(w8 + 4194304);          // 2 MB
    __bf16* Zbh = (__bf16*)(w8 + 6291456);         // 1 MB
    __bf16* Zbl = (__bf16*)(w8 + 7340032);         // 1 MB
    float*  Pm  = (float*)(w8 + 8388608);          // 64 KB

    k_cvt_w<<<768, 256, 0, stream>>>(s_wq, s_wk, s_wv, s_wo, s_fw1, s_fw2, Wswz);

    k_latent<<<A_N, 1024, 0, stream>>>(z, Wswz, s_bo, s_ln1g, s_ln1b,
                                       s_fb1, s_fb2, s_ln2g, s_ln2b,
                                       Zprior, Zbh, Zbl);

    k_cann_gemm<<<dim3(FLATD / 64, 3), 512, 0, stream>>>(Zbh, Zbl, q_w, k_w, v_w,
                                                         q_b, k_b, v_b, Qb, Kb, Vb);

    k_cann_scores<<<A_N / 2, 512, 0, stream>>>(Qb, Kb, Pm);
    k_cann_out<<<dim3(4, 16), 256, 0, stream>>>(Pm, Vb, Hout);
}